// Round 7
// baseline (202.906 us; speedup 1.0000x reference)
//
#include <hip/hip_runtime.h>
#include <stdint.h>

#define NB 4
#define CC 256
#define NN 4096   // H*W = 64*64
#define KITERS 32 // k-steps per attention chunk (chunk = 1024)
#define WAIT_LGKM0 0xC07F  // s_waitcnt lgkmcnt(0), vmcnt/expcnt untouched

typedef __attribute__((ext_vector_type(8))) _Float16 half8;   // MFMA A/B frag (4 VGPR)
typedef __attribute__((ext_vector_type(4))) _Float16 half4;   // 8B packed store
typedef __attribute__((ext_vector_type(2))) _Float16 half2v;
typedef __attribute__((ext_vector_type(4))) float floatx4;    // 16x16 acc
typedef __attribute__((ext_vector_type(16))) float float16v;  // 32x32 acc
typedef __attribute__((ext_vector_type(4))) int intx4;        // 16B copy

__device__ __forceinline__ void cvt16v(float4 a, float4 b, float4 c, float4 d,
                                       half8& lo, half8& hi) {
  lo[0] = (_Float16)a.x; lo[1] = (_Float16)a.y; lo[2] = (_Float16)a.z; lo[3] = (_Float16)a.w;
  lo[4] = (_Float16)b.x; lo[5] = (_Float16)b.y; lo[6] = (_Float16)b.z; lo[7] = (_Float16)b.w;
  hi[0] = (_Float16)c.x; hi[1] = (_Float16)c.y; hi[2] = (_Float16)c.z; hi[3] = (_Float16)c.w;
  hi[4] = (_Float16)d.x; hi[5] = (_Float16)d.y; hi[6] = (_Float16)d.z; hi[7] = (_Float16)d.w;
}

// pack two f32 -> one u32 of two f16 (RTE, identical to scalar casts)
__device__ __forceinline__ int packh2(float a, float b) {
  half2v p; p[0] = (_Float16)a; p[1] = (_Float16)b;
  return __builtin_bit_cast(int, p);
}

// async global->LDS, 16B per lane; lds dest = wave-uniform base + lane*16.
// PROVEN FORM (R1/R4): global side cast via uintptr, LDS side cast DIRECTLY
// from the generic pointer. PITFALL (R2): LDS side via uintptr_t reinterprets
// the FLAT address as an LDS offset -> garbage.
__device__ __forceinline__ void a16(const _Float16* g, _Float16* l) {
  __builtin_amdgcn_global_load_lds(
      (__attribute__((address_space(1))) void*)(uintptr_t)g,
      (__attribute__((address_space(3))) void*)l, 16, 0, 0);
}

// ---------------------------------------------------------------------------
// Fused transpose + Q/K/V projections -> FRAG-MAJOR (swizzled) outputs.
// Reads F [b][c][n] fp32 directly; per k-iter transposes 32c x 128n via LDS.
// z=0: Q = Wf.Fc   z=1: K = Wg.Fs   z=2: Vt = (Fs^T.Wh^T)^T
// grid (64, NB, 3), 256 threads, 3 blocks/CU.  (R1-exact, known-good)
// ---------------------------------------------------------------------------
__global__ __launch_bounds__(256, 3) void k_qkv(const float* __restrict__ Fc,
                                                const float* __restrict__ Fs,
                                                const float* __restrict__ Wf,
                                                const float* __restrict__ Wg,
                                                const float* __restrict__ Wh,
                                                const float* __restrict__ bf,
                                                const float* __restrict__ bg,
                                                const float* __restrict__ bh,
                                                _Float16* __restrict__ Qs,
                                                _Float16* __restrict__ Ks,
                                                _Float16* __restrict__ Vs) {
  __shared__ float tmp[32][132];     // 16.9 KB fp32 transpose staging
  __shared__ _Float16 As[128][40];   // 10 KB
  __shared__ _Float16 Bs[128][40];   // 10 KB
  const int z = blockIdx.z, bz = blockIdx.y;
  const float* F = ((z == 0) ? Fc : Fs) + (size_t)bz * CC * NN;
  const float* W = (z == 0) ? Wf : ((z == 1) ? Wg : Wh);
  const float* bias = (z == 0) ? bf : ((z == 1) ? bg : bh);
  int mt, nt;
  if (z < 2) { mt = blockIdx.x >> 5; nt = blockIdx.x & 31; }  // M=d(256), N=n(4096)
  else       { mt = blockIdx.x >> 1; nt = blockIdx.x & 1;  }  // M=n(4096), N=d(256)
  const int m0 = mt * 128, n0 = nt * 128;
  const int xn0 = (z < 2) ? n0 : m0;  // spatial base of the F tile (X side)
  const int wd0 = (z < 2) ? m0 : n0;  // W row base (channel side)
  const int tid = threadIdx.x;
  const int wave = tid >> 6, lane = tid & 63, quad = lane >> 4, l15 = lane & 15;
  const int wm = (wave >> 1) * 64, wn = (wave & 1) * 64;

  floatx4 acc[4][4];
#pragma unroll
  for (int i = 0; i < 4; i++)
#pragma unroll
    for (int j = 0; j < 4; j++) acc[i][j] = (floatx4){0.f, 0.f, 0.f, 0.f};

  const int srow = tid >> 1, shalf = (tid & 1) * 16;   // W staging
  const int fc = tid >> 3, fn = (tid & 7) * 16;        // F load (c-row, n-off)
  const int xr = tid >> 1, xh = (tid & 1) * 16;        // transposed read

  float4 wr0, wr1, wr2, wr3, fr0, fr1, fr2, fr3;
  {
    const float4* wp = (const float4*)(W + (size_t)(wd0 + srow) * 256 + 0 + shalf);
    wr0 = wp[0]; wr1 = wp[1]; wr2 = wp[2]; wr3 = wp[3];
    const float4* fp = (const float4*)(F + (size_t)(0 + fc) * NN + xn0 + fn);
    fr0 = fp[0]; fr1 = fp[1]; fr2 = fp[2]; fr3 = fp[3];
  }

  for (int kk = 0; kk < 256; kk += 32) {
    __syncthreads();  // 1: prev frag+tmp reads done
    *(float4*)&tmp[fc][fn + 0] = fr0;
    *(float4*)&tmp[fc][fn + 4] = fr1;
    *(float4*)&tmp[fc][fn + 8] = fr2;
    *(float4*)&tmp[fc][fn + 12] = fr3;
    half8 w_lo, w_hi;
    cvt16v(wr0, wr1, wr2, wr3, w_lo, w_hi);
    if (z < 2) {
      *(half8*)&As[srow][shalf] = w_lo;
      *(half8*)&As[srow][shalf + 8] = w_hi;
    } else {
      *(half8*)&Bs[srow][shalf] = w_lo;
      *(half8*)&Bs[srow][shalf + 8] = w_hi;
    }
    __syncthreads();  // 2: tmp + W-side visible
    if (kk + 32 < 256) {  // prefetch next iter
      const float4* wp = (const float4*)(W + (size_t)(wd0 + srow) * 256 + kk + 32 + shalf);
      wr0 = wp[0]; wr1 = wp[1]; wr2 = wp[2]; wr3 = wp[3];
      const float4* fp = (const float4*)(F + (size_t)(kk + 32 + fc) * NN + xn0 + fn);
      fr0 = fp[0]; fr1 = fp[1]; fr2 = fp[2]; fr3 = fp[3];
    }
    half8 xlo, xhi;
#pragma unroll
    for (int i = 0; i < 8; i++) xlo[i] = (_Float16)tmp[xh + i][xr];
#pragma unroll
    for (int i = 0; i < 8; i++) xhi[i] = (_Float16)tmp[xh + 8 + i][xr];
    if (z < 2) {
      *(half8*)&Bs[xr][xh] = xlo;
      *(half8*)&Bs[xr][xh + 8] = xhi;
    } else {
      *(half8*)&As[xr][xh] = xlo;
      *(half8*)&As[xr][xh + 8] = xhi;
    }
    __syncthreads();  // 3: As/Bs complete
    half8 af[4], bfr[4];
#pragma unroll
    for (int mb = 0; mb < 4; mb++) af[mb] = *(const half8*)&As[wm + mb * 16 + l15][quad * 8];
#pragma unroll
    for (int nb = 0; nb < 4; nb++) bfr[nb] = *(const half8*)&Bs[wn + nb * 16 + l15][quad * 8];
#pragma unroll
    for (int mb = 0; mb < 4; mb++)
#pragma unroll
      for (int nb = 0; nb < 4; nb++)
        acc[mb][nb] = __builtin_amdgcn_mfma_f32_16x16x32_f16(af[mb], bfr[nb], acc[mb][nb], 0, 0, 0);
  }

  if (z < 2) {
    _Float16* op = (z == 0 ? Qs : Ks) + (size_t)bz * NN * CC;
#pragma unroll
    for (int mb = 0; mb < 4; mb++) {
      int d0 = m0 + wm + mb * 16 + quad * 4;
      float b0 = bias[d0], b1 = bias[d0 + 1], b2 = bias[d0 + 2], b3 = bias[d0 + 3];
      const int cs = d0 >> 4, hh = (d0 >> 3) & 1, j0 = d0 & 7;
#pragma unroll
      for (int nb = 0; nb < 4; nb++) {
        int n_ = n0 + wn + nb * 16 + l15;
        int kt = n_ >> 5, ql_ = n_ & 31;
        half4 pk;
        pk[0] = (_Float16)(acc[mb][nb][0] + b0);
        pk[1] = (_Float16)(acc[mb][nb][1] + b1);
        pk[2] = (_Float16)(acc[mb][nb][2] + b2);
        pk[3] = (_Float16)(acc[mb][nb][3] + b3);
        size_t idx = ((size_t)(kt * 16 + cs) * 64 + ql_ + 32 * hh) * 8 + j0;
        *(half4*)(op + idx) = pk;
      }
    }
  } else {
    _Float16* op = Vs + (size_t)bz * NN * CC;
#pragma unroll
    for (int mb = 0; mb < 4; mb++) {
      int nq0 = m0 + wm + mb * 16 + quad * 4;
      const int kt = nq0 >> 5, krel = nq0 & 31;
      const int hk = krel >> 4, hh = (krel >> 3) & 1, j0 = krel & 7;
#pragma unroll
      for (int nb = 0; nb < 4; nb++) {
        int d = n0 + wn + nb * 16 + l15;
        int ql_ = d & 31, g = (d >> 5) & 7;
        float bv = bias[d];
        half4 pk;
        pk[0] = (_Float16)(acc[mb][nb][0] + bv);
        pk[1] = (_Float16)(acc[mb][nb][1] + bv);
        pk[2] = (_Float16)(acc[mb][nb][2] + bv);
        pk[3] = (_Float16)(acc[mb][nb][3] + bv);
        size_t idx = (((size_t)(kt * 8 + g) * 2 + hk) * 64 + ql_ + 32 * hh) * 8 + j0;
        *(half4*)(op + idx) = pk;
      }
    }
  }
}

// ---------------------------------------------------------------------------
// Flash attention v9 (R1-exact, harness-verified): global_load_lds K/V dbuf,
// 1 barrier/iter, in-register P via cvt_pk+permlane32_swap (DISTINCT operands
// only — R3 pitfall), setprio. Stagger removed (R4: neutral).
// grid (32 qtiles, 4 chunks, NB), 256 threads.
// ---------------------------------------------------------------------------
__global__ __launch_bounds__(256, 2) void k_attn(const _Float16* __restrict__ Q,
                                                 const _Float16* __restrict__ K,
                                                 const _Float16* __restrict__ Vt,
                                                 _Float16* __restrict__ Opart,
                                                 float2* __restrict__ Ml) {
  __shared__ _Float16 smem[8192 * 4];  // K dbuf 32KB | V dbuf 32KB
  const int tid = threadIdx.x;
  const int wave = tid >> 6, lane = tid & 63;

  const int qt = blockIdx.x, ck = blockIdx.y, b = blockIdx.z;
  const int ql = lane & 31, h = lane >> 5;
  const int q0 = qt * 128 + wave * 32;
  const _Float16* Qb = Q + (size_t)b * NN * CC;
  const _Float16* Kg = K + (size_t)b * NN * CC;
  const _Float16* Vg = Vt + (size_t)b * NN * CC;
  const int kt_base = ck * KITERS;
  const int so = wave * 512;             // per-wave LDS stage base (halves)
  const int go = wave * 512 + lane * 8;  // per-lane global offset (halves)

  const int ktq = q0 >> 5;
  half8 qf[16];
#pragma unroll
  for (int cs = 0; cs < 16; cs++)
    qf[cs] = *(const half8*)(Qb + ((size_t)(ktq * 16 + cs) * 64 + lane) * 8);

  float16v Oa[8];
#pragma unroll
  for (int g = 0; g < 8; g++)
#pragma unroll
    for (int i = 0; i < 16; i++) Oa[g][i] = 0.f;

  float m_run = -1e30f, l_run = 0.f;
  half8 pf0, pf1;  // previous-iter P fragments, live in registers
#pragma unroll
  for (int i = 0; i < 8; i++) { pf0[i] = (_Float16)0.f; pf1[i] = (_Float16)0.f; }

  // prologue: stage K[0] -> Kbuf0
  {
    const _Float16* Kt = Kg + (size_t)kt_base * 8192;
#pragma unroll
    for (int p = 0; p < 4; p++) a16(Kt + p * 2048 + go, smem + p * 2048 + so);
  }

  for (int t = 0; t < KITERS; t++) {
    asm volatile("s_waitcnt vmcnt(0)" ::: "memory");  // K[t] (+V[t-1]) landed
    __builtin_amdgcn_s_barrier();
    // stage V[t] -> Vbuf[t&1]; K[t+1] -> Kbuf[(t+1)&1]
    {
      const _Float16* Vtile = Vg + (size_t)(kt_base + t) * 8192;
      _Float16* Vw = smem + (2 + (t & 1)) * 8192;
#pragma unroll
      for (int p = 0; p < 4; p++) a16(Vtile + p * 2048 + go, Vw + p * 2048 + so);
      if (t + 1 < KITERS) {
        const _Float16* Kt = Kg + (size_t)(kt_base + t + 1) * 8192;
        _Float16* Kw = smem + ((t + 1) & 1) * 8192;
#pragma unroll
        for (int p = 0; p < 4; p++) a16(Kt + p * 2048 + go, Kw + p * 2048 + so);
      }
    }
    const _Float16* Kl = smem + (t & 1) * 8192;

    // ---- MFMA burst: S_i and PV_i interleaved; PV in ks-outer order:
    //   i<8: Oa[i]   += V[2i]  ·pf0     i>=8: Oa[i-8] += V[2(i-8)+1]·pf1
    float16v s, s2;
#pragma unroll
    for (int i = 0; i < 16; i++) { s[i] = 0.f; s2[i] = 0.f; }
    __builtin_amdgcn_s_setprio(1);
    if (t > 0) {
      const _Float16* Vr = smem + (2 + ((t - 1) & 1)) * 8192;
#pragma unroll
      for (int i = 0; i < 16; i++) {
        half8 kf = *(const half8*)(Kl + i * 512 + lane * 8);
        if (i & 1)
          s2 = __builtin_amdgcn_mfma_f32_32x32x16_f16(kf, qf[i], s2, 0, 0, 0);
        else
          s = __builtin_amdgcn_mfma_f32_32x32x16_f16(kf, qf[i], s, 0, 0, 0);
        const int u = i & 7, ks = i >> 3;
        half8 vf = *(const half8*)(Vr + (2 * u + ks) * 512 + lane * 8);
        Oa[u] = __builtin_amdgcn_mfma_f32_32x32x16_f16(vf, ks ? pf1 : pf0, Oa[u], 0, 0, 0);
      }
    } else {
#pragma unroll
      for (int cs = 0; cs < 16; cs += 2) {
        half8 kfa = *(const half8*)(Kl + cs * 512 + lane * 8);
        s = __builtin_amdgcn_mfma_f32_32x32x16_f16(kfa, qf[cs], s, 0, 0, 0);
        half8 kfb = *(const half8*)(Kl + (cs + 1) * 512 + lane * 8);
        s2 = __builtin_amdgcn_mfma_f32_32x32x16_f16(kfb, qf[cs + 1], s2, 0, 0, 0);
      }
    }
    __builtin_amdgcn_s_setprio(0);
#pragma unroll
    for (int i = 0; i < 16; i++) s[i] += s2[i];

    // ---- lazy online softmax (per-lane), tree reductions
    float t0 = fmaxf(s[0], s[1]), t1 = fmaxf(s[2], s[3]);
    float t2 = fmaxf(s[4], s[5]), t3 = fmaxf(s[6], s[7]);
    float t4 = fmaxf(s[8], s[9]), t5 = fmaxf(s[10], s[11]);
    float t6 = fmaxf(s[12], s[13]), t7 = fmaxf(s[14], s[15]);
    t0 = fmaxf(t0, t1); t2 = fmaxf(t2, t3); t4 = fmaxf(t4, t5); t6 = fmaxf(t6, t7);
    float tmax = fmaxf(fmaxf(t0, t2), fmaxf(t4, t6));
    tmax = fmaxf(tmax, __shfl_xor(tmax, 32));
    bool need = tmax > m_run + 8.0f;
    if (__any((int)need)) {
      float mN = need ? tmax : m_run;
      float alpha = __expf(m_run - mN);
      m_run = mN;
      l_run *= alpha;
#pragma unroll
      for (int g = 0; g < 8; g++)
#pragma unroll
        for (int i = 0; i < 16; i++) Oa[g][i] *= alpha;
    }
#pragma unroll
    for (int i = 0; i < 16; i++) s[i] = __expf(s[i] - m_run);
    float u0 = (s[0] + s[1]) + (s[2] + s[3]);
    float u1 = (s[4] + s[5]) + (s[6] + s[7]);
    float u2 = (s[8] + s[9]) + (s[10] + s[11]);
    float u3 = (s[12] + s[13]) + (s[14] + s[15]);
    float ts = (u0 + u1) + (u2 + u3);
    ts += __shfl_xor(ts, 32);
    l_run += ts;

    // ---- P -> registers: pack f16 pairs, swap halves across lane 32 boundary.
    {
      int A01 = packh2(s[0], s[1]), B23 = packh2(s[2], s[3]);
      int C45 = packh2(s[4], s[5]), D67 = packh2(s[6], s[7]);
      int E01 = packh2(s[8], s[9]), F23 = packh2(s[10], s[11]);
      int G45 = packh2(s[12], s[13]), H67 = packh2(s[14], s[15]);
      auto rA = __builtin_amdgcn_permlane32_swap(A01, C45, false, false);
      auto rB = __builtin_amdgcn_permlane32_swap(B23, D67, false, false);
      auto rC = __builtin_amdgcn_permlane32_swap(E01, G45, false, false);
      auto rD = __builtin_amdgcn_permlane32_swap(F23, H67, false, false);
      intx4 w0, w1;
      w0[0] = rA[0]; w0[1] = rB[0]; w0[2] = rA[1]; w0[3] = rB[1];
      w1[0] = rC[0]; w1[1] = rD[0]; w1[2] = rC[1]; w1[3] = rD[1];
      pf0 = __builtin_bit_cast(half8, w0);
      pf1 = __builtin_bit_cast(half8, w1);
    }
  }

  // ---- tail: PV for last tile (ks-outer, same per-chain order)
  asm volatile("s_waitcnt vmcnt(0)" ::: "memory");  // V[KITERS-1] landed
  __builtin_amdgcn_s_barrier();
  {
    const _Float16* Vr = smem + (2 + ((KITERS - 1) & 1)) * 8192;
#pragma unroll
    for (int u = 0; u < 8; u++) {
      half8 vfa = *(const half8*)(Vr + (2 * u) * 512 + lane * 8);
      Oa[u] = __builtin_amdgcn_mfma_f32_32x32x16_f16(vfa, pf0, Oa[u], 0, 0, 0);
    }
#pragma unroll
    for (int u = 0; u < 8; u++) {
      half8 vfb = *(const half8*)(Vr + (2 * u + 1) * 512 + lane * 8);
      Oa[u] = __builtin_amdgcn_mfma_f32_32x32x16_f16(vfb, pf1, Oa[u], 0, 0, 0);
    }
  }

  // ---- epilogue: normalize, per-wave LDS transpose, coalesced store
  float invl = 1.f / l_run;
  __syncthreads();
  float* ot = (float*)smem + wave * (32 * 33);
  _Float16* Opb = Opart + ((size_t)ck * NB + b) * NN * CC;
  const int qr = lane >> 1;
  const int chalf = (lane & 1) * 16;
#pragma unroll
  for (int g = 0; g < 8; g++) {
#pragma unroll
    for (int r = 0; r < 16; r++)
      ot[((r & 3) + 8 * (r >> 2) + 4 * h) * 33 + ql] = Oa[g][r] * invl;
    __builtin_amdgcn_s_waitcnt(WAIT_LGKM0);
    half8 o0, o1;
#pragma unroll
    for (int i = 0; i < 8; i++) o0[i] = (_Float16)ot[(chalf + i) * 33 + qr];
#pragma unroll
    for (int i = 0; i < 8; i++) o1[i] = (_Float16)ot[(chalf + 8 + i) * 33 + qr];
    _Float16* gp = Opb + (size_t)(q0 + qr) * CC + g * 32 + chalf;
    *(half8*)gp = o0;
    *(half8*)(gp + 8) = o1;
    __builtin_amdgcn_s_waitcnt(WAIT_LGKM0);
  }
  if (h == 0) {
    float2 ml; ml.x = m_run; ml.y = l_run;
    Ml[((size_t)ck * NB + b) * NN + q0 + ql] = ml;
  }
}

// ---------------------------------------------------------------------------
// Final conv with fused split-K merge. v15: K-step 128 (2 iters, 4 barriers)
// + EARLY prefetch (issued right after the merge consumes the regs, landing
// window = full iteration instead of one MFMA phase). Pad 140: frag reads
// conflict-free (stride 280B = 6 dw mod 32), tile writes <=4-way.
// Per-acc MFMA chain order identical (ks=0..3 over kk in {0,128} == old
// kk=0,32,...,224) -> bit-exact. grid (128, NB), 256 thr, 2 blocks/CU (53.8KB).
// ---------------------------------------------------------------------------
__global__ __launch_bounds__(256, 2) void k_out(const _Float16* __restrict__ Opart,
                                                const float2* __restrict__ Ml,
                                                const float* __restrict__ Wo,
                                                const float* __restrict__ bo,
                                                float* __restrict__ out) {
  __shared__ _Float16 As[64][140];   // 17.5 KB (merged O rows, 128-c slice)
  __shared__ _Float16 Bs[128][140];  // 35 KB  (Wo rows, 128-c slice)
  const int bz = blockIdx.y;
  const int mt = blockIdx.x >> 1, nt = blockIdx.x & 1;  // 64 mtiles x 2 ntiles
  const int m0 = mt * 64, n0 = nt * 128;
  const int tid = threadIdx.x;
  const int wave = tid >> 6, lane = tid & 63, quad = lane >> 4, l15 = lane & 15;
  const int wn = wave * 32;

  floatx4 acc[4][2];
#pragma unroll
  for (int i = 0; i < 4; i++)
#pragma unroll
    for (int j = 0; j < 2; j++) acc[i][j] = (floatx4){0.f, 0.f, 0.f, 0.f};

  const int arow = tid >> 2, acol = (tid & 3) * 32;   // A: 64 rows x 128 c
  const int brow = tid >> 1, bcol = (tid & 1) * 64;   // B: 128 rows x 128 c

  // merge weights for this thread's fixed row q = m0 + arow
  const size_t qi = (size_t)bz * NN + m0 + arow;
  float2 a0 = Ml[qi], a1 = Ml[(size_t)NB * NN + qi];
  float2 a2 = Ml[(size_t)2 * NB * NN + qi], a3 = Ml[(size_t)3 * NB * NN + qi];
  float M = fmaxf(fmaxf(a0.x, a1.x), fmaxf(a2.x, a3.x));
  float w0 = __expf(a0.x - M) * a0.y, w1 = __expf(a1.x - M) * a1.y;
  float w2 = __expf(a2.x - M) * a2.y, w3 = __expf(a3.x - M) * a3.y;
  float inv = 1.f / (w0 + w1 + w2 + w3);
  w0 *= inv; w1 *= inv; w2 *= inv; w3 *= inv;
  const size_t ps = (size_t)NB * NN * CC;
  const _Float16* prow = Opart + qi * CC;

  // preload kk=0: 4 planes x 4 half8 of O, 16 float4 of Wo
  half8 pA[4][4];
  float4 wr[16];
  {
    const _Float16* pr = prow + acol;
#pragma unroll
    for (int pl = 0; pl < 4; pl++)
#pragma unroll
      for (int q = 0; q < 4; q++)
        pA[pl][q] = *(const half8*)(pr + (size_t)pl * ps + q * 8);
    const float4* wp = (const float4*)(Wo + (size_t)(n0 + brow) * 256 + bcol);
#pragma unroll
    for (int i = 0; i < 16; i++) wr[i] = wp[i];
  }

  for (int kk = 0; kk < 256; kk += 128) {
    // merge 4 planes -> f16 A rows (consumes pA)
    half8 ma[4];
#pragma unroll
    for (int q = 0; q < 4; q++)
#pragma unroll
      for (int i = 0; i < 8; i++)
        ma[q][i] = (_Float16)(w0 * (float)pA[0][q][i] + w1 * (float)pA[1][q][i] +
                              w2 * (float)pA[2][q][i] + w3 * (float)pA[3][q][i]);
    half8 bl[4], bh[4];
#pragma unroll
    for (int q = 0; q < 4; q++) cvt16v(wr[4 * q], wr[4 * q + 1], wr[4 * q + 2], wr[4 * q + 3], bl[q], bh[q]);
    // EARLY prefetch: issue next-slice loads NOW (regs free after merge/cvt);
    // landing window = sync + LDS writes + sync + 32 MFMA (~full iteration).
    if (kk + 128 < 256) {
      const _Float16* pr = prow + kk + 128 + acol;
#pragma unroll
      for (int pl = 0; pl < 4; pl++)
#pragma unroll
        for (int q = 0; q < 4; q++)
          pA[pl][q] = *(const half8*)(pr + (size_t)pl * ps + q * 8);
      const float4* wp = (const float4*)(Wo + (size_t)(n0 + brow) * 256 + kk + 128 + bcol);
#pragma unroll
      for (int i = 0; i < 16; i++) wr[i] = wp[i];
    }
    __syncthreads();  // prev frag reads done
#pragma unroll
    for (int q = 0; q < 4; q++) *(half8*)&As[arow][acol + q * 8] = ma[q];
#pragma unroll
    for (int q = 0; q < 4; q++) {
      *(half8*)&Bs[brow][bcol + q * 16] = bl[q];
      *(half8*)&Bs[brow][bcol + q * 16 + 8] = bh[q];
    }
    __syncthreads();  // tiles visible
#pragma unroll
    for (int ks = 0; ks < 4; ks++) {
      half8 af[4], bfr[2];
#pragma unroll
      for (int mb = 0; mb < 4; mb++)
        af[mb] = *(const half8*)&As[mb * 16 + l15][ks * 32 + quad * 8];
#pragma unroll
      for (int nb = 0; nb < 2; nb++)
        bfr[nb] = *(const half8*)&Bs[wn + nb * 16 + l15][ks * 32 + quad * 8];
#pragma unroll
      for (int mb = 0; mb < 4; mb++)
#pragma unroll
        for (int nb = 0; nb < 2; nb++)
          acc[mb][nb] = __builtin_amdgcn_mfma_f32_16x16x32_f16(af[mb], bfr[nb], acc[mb][nb], 0, 0, 0);
    }
  }

  float* op = out + (size_t)bz * NN * CC;
#pragma unroll
  for (int mb = 0; mb < 4; mb++) {
    int nq0 = m0 + mb * 16 + quad * 4;  // spatial
#pragma unroll
    for (int nb = 0; nb < 2; nb++) {
      int d = n0 + wn + nb * 16 + l15;
      float bv = bo[d];
      floatx4 pk;
      pk[0] = acc[mb][nb][0] + bv;
      pk[1] = acc[mb][nb][1] + bv;
      pk[2] = acc[mb][nb][2] + bv;
      pk[3] = acc[mb][nb][3] + bv;
      *(floatx4*)(op + (size_t)d * NN + nq0) = pk;
    }
  }
}

// ---------------------------------------------------------------------------
extern "C" void kernel_launch(void* const* d_in, const int* in_sizes, int n_in,
                              void* d_out, int out_size, void* d_ws, size_t ws_size,
                              hipStream_t stream) {
  const float* Fc = (const float*)d_in[0];
  const float* Fs = (const float*)d_in[1];
  const float* Wf = (const float*)d_in[2];
  const float* bf_ = (const float*)d_in[3];
  const float* Wg = (const float*)d_in[4];
  const float* bg = (const float*)d_in[5];
  const float* Wh = (const float*)d_in[6];
  const float* bh = (const float*)d_in[7];
  const float* Wo = (const float*)d_in[8];
  const float* bo = (const float*)d_in[9];

  char* ws = (char*)d_ws;
  const size_t sz = (size_t)NB * NN * CC * sizeof(_Float16);  // 8 MB per plane
  _Float16* Opart = (_Float16*)(ws + 0 * sz);  // planes 0..3 (split-K partials)
  _Float16* Qs = (_Float16*)(ws + 4 * sz);     // swizzled
  _Float16* Ks = (_Float16*)(ws + 5 * sz);
  _Float16* Vs = (_Float16*)(ws + 6 * sz);
  float2* Ml = (float2*)(ws + 7 * sz);         // 512 KB

  k_qkv<<<dim3(64, NB, 3), 256, 0, stream>>>(Fc, Fs, Wf, Wg, Wh, bf_, bg, bh, Qs, Ks, Vs);
  k_attn<<<dim3(32, 4, NB), 256, 0, stream>>>(Qs, Ks, Vs, Opart, Ml);
  k_out<<<dim3(128, NB), 256, 0, stream>>>(Opart, Ml, Wo, bo, (float*)d_out);
}

// Round 8
// 202.490 us; speedup vs baseline: 1.0021x; 1.0021x over previous
//
#include <hip/hip_runtime.h>
#include <stdint.h>

#define NB 4
#define CC 256
#define NN 4096   // H*W = 64*64
#define KITERS 32 // k-steps per attention chunk (chunk = 1024)
#define WAIT_LGKM0 0xC07F  // s_waitcnt lgkmcnt(0), vmcnt/expcnt untouched

typedef __attribute__((ext_vector_type(8))) _Float16 half8;   // MFMA A/B frag (4 VGPR)
typedef __attribute__((ext_vector_type(4))) _Float16 half4;   // 8B packed store
typedef __attribute__((ext_vector_type(2))) _Float16 half2v;
typedef __attribute__((ext_vector_type(4))) float floatx4;    // 16x16 acc
typedef __attribute__((ext_vector_type(16))) float float16v;  // 32x32 acc
typedef __attribute__((ext_vector_type(4))) int intx4;        // 16B copy

__device__ __forceinline__ void cvt16v(float4 a, float4 b, float4 c, float4 d,
                                       half8& lo, half8& hi) {
  lo[0] = (_Float16)a.x; lo[1] = (_Float16)a.y; lo[2] = (_Float16)a.z; lo[3] = (_Float16)a.w;
  lo[4] = (_Float16)b.x; lo[5] = (_Float16)b.y; lo[6] = (_Float16)b.z; lo[7] = (_Float16)b.w;
  hi[0] = (_Float16)c.x; hi[1] = (_Float16)c.y; hi[2] = (_Float16)c.z; hi[3] = (_Float16)c.w;
  hi[4] = (_Float16)d.x; hi[5] = (_Float16)d.y; hi[6] = (_Float16)d.z; hi[7] = (_Float16)d.w;
}

// pack two f32 -> one u32 of two f16 (RTE, identical to scalar casts)
__device__ __forceinline__ int packh2(float a, float b) {
  half2v p; p[0] = (_Float16)a; p[1] = (_Float16)b;
  return __builtin_bit_cast(int, p);
}

// async global->LDS, 16B per lane; lds dest = wave-uniform base + lane*16.
// PROVEN FORM (R1/R4): global side cast via uintptr, LDS side cast DIRECTLY
// from the generic pointer. PITFALL (R2): LDS side via uintptr_t reinterprets
// the FLAT address as an LDS offset -> garbage.
__device__ __forceinline__ void a16(const _Float16* g, _Float16* l) {
  __builtin_amdgcn_global_load_lds(
      (__attribute__((address_space(1))) void*)(uintptr_t)g,
      (__attribute__((address_space(3))) void*)l, 16, 0, 0);
}

// ---------------------------------------------------------------------------
// Fused transpose + Q/K/V projections -> FRAG-MAJOR (swizzled) outputs.
// Reads F [b][c][n] fp32 directly; per k-iter transposes 32c x 128n via LDS.
// z=0: Q = Wf.Fc   z=1: K = Wg.Fs   z=2: Vt = (Fs^T.Wh^T)^T
// grid (64, NB, 3), 256 threads, 3 blocks/CU.  (R1-exact, known-good)
// ---------------------------------------------------------------------------
__global__ __launch_bounds__(256, 3) void k_qkv(const float* __restrict__ Fc,
                                                const float* __restrict__ Fs,
                                                const float* __restrict__ Wf,
                                                const float* __restrict__ Wg,
                                                const float* __restrict__ Wh,
                                                const float* __restrict__ bf,
                                                const float* __restrict__ bg,
                                                const float* __restrict__ bh,
                                                _Float16* __restrict__ Qs,
                                                _Float16* __restrict__ Ks,
                                                _Float16* __restrict__ Vs) {
  __shared__ float tmp[32][132];     // 16.9 KB fp32 transpose staging
  __shared__ _Float16 As[128][40];   // 10 KB
  __shared__ _Float16 Bs[128][40];   // 10 KB
  const int z = blockIdx.z, bz = blockIdx.y;
  const float* F = ((z == 0) ? Fc : Fs) + (size_t)bz * CC * NN;
  const float* W = (z == 0) ? Wf : ((z == 1) ? Wg : Wh);
  const float* bias = (z == 0) ? bf : ((z == 1) ? bg : bh);
  int mt, nt;
  if (z < 2) { mt = blockIdx.x >> 5; nt = blockIdx.x & 31; }  // M=d(256), N=n(4096)
  else       { mt = blockIdx.x >> 1; nt = blockIdx.x & 1;  }  // M=n(4096), N=d(256)
  const int m0 = mt * 128, n0 = nt * 128;
  const int xn0 = (z < 2) ? n0 : m0;  // spatial base of the F tile (X side)
  const int wd0 = (z < 2) ? m0 : n0;  // W row base (channel side)
  const int tid = threadIdx.x;
  const int wave = tid >> 6, lane = tid & 63, quad = lane >> 4, l15 = lane & 15;
  const int wm = (wave >> 1) * 64, wn = (wave & 1) * 64;

  floatx4 acc[4][4];
#pragma unroll
  for (int i = 0; i < 4; i++)
#pragma unroll
    for (int j = 0; j < 4; j++) acc[i][j] = (floatx4){0.f, 0.f, 0.f, 0.f};

  const int srow = tid >> 1, shalf = (tid & 1) * 16;   // W staging
  const int fc = tid >> 3, fn = (tid & 7) * 16;        // F load (c-row, n-off)
  const int xr = tid >> 1, xh = (tid & 1) * 16;        // transposed read

  float4 wr0, wr1, wr2, wr3, fr0, fr1, fr2, fr3;
  {
    const float4* wp = (const float4*)(W + (size_t)(wd0 + srow) * 256 + 0 + shalf);
    wr0 = wp[0]; wr1 = wp[1]; wr2 = wp[2]; wr3 = wp[3];
    const float4* fp = (const float4*)(F + (size_t)(0 + fc) * NN + xn0 + fn);
    fr0 = fp[0]; fr1 = fp[1]; fr2 = fp[2]; fr3 = fp[3];
  }

  for (int kk = 0; kk < 256; kk += 32) {
    __syncthreads();  // 1: prev frag+tmp reads done
    *(float4*)&tmp[fc][fn + 0] = fr0;
    *(float4*)&tmp[fc][fn + 4] = fr1;
    *(float4*)&tmp[fc][fn + 8] = fr2;
    *(float4*)&tmp[fc][fn + 12] = fr3;
    half8 w_lo, w_hi;
    cvt16v(wr0, wr1, wr2, wr3, w_lo, w_hi);
    if (z < 2) {
      *(half8*)&As[srow][shalf] = w_lo;
      *(half8*)&As[srow][shalf + 8] = w_hi;
    } else {
      *(half8*)&Bs[srow][shalf] = w_lo;
      *(half8*)&Bs[srow][shalf + 8] = w_hi;
    }
    __syncthreads();  // 2: tmp + W-side visible
    if (kk + 32 < 256) {  // prefetch next iter
      const float4* wp = (const float4*)(W + (size_t)(wd0 + srow) * 256 + kk + 32 + shalf);
      wr0 = wp[0]; wr1 = wp[1]; wr2 = wp[2]; wr3 = wp[3];
      const float4* fp = (const float4*)(F + (size_t)(kk + 32 + fc) * NN + xn0 + fn);
      fr0 = fp[0]; fr1 = fp[1]; fr2 = fp[2]; fr3 = fp[3];
    }
    half8 xlo, xhi;
#pragma unroll
    for (int i = 0; i < 8; i++) xlo[i] = (_Float16)tmp[xh + i][xr];
#pragma unroll
    for (int i = 0; i < 8; i++) xhi[i] = (_Float16)tmp[xh + 8 + i][xr];
    if (z < 2) {
      *(half8*)&Bs[xr][xh] = xlo;
      *(half8*)&Bs[xr][xh + 8] = xhi;
    } else {
      *(half8*)&As[xr][xh] = xlo;
      *(half8*)&As[xr][xh + 8] = xhi;
    }
    __syncthreads();  // 3: As/Bs complete
    half8 af[4], bfr[4];
#pragma unroll
    for (int mb = 0; mb < 4; mb++) af[mb] = *(const half8*)&As[wm + mb * 16 + l15][quad * 8];
#pragma unroll
    for (int nb = 0; nb < 4; nb++) bfr[nb] = *(const half8*)&Bs[wn + nb * 16 + l15][quad * 8];
#pragma unroll
    for (int mb = 0; mb < 4; mb++)
#pragma unroll
      for (int nb = 0; nb < 4; nb++)
        acc[mb][nb] = __builtin_amdgcn_mfma_f32_16x16x32_f16(af[mb], bfr[nb], acc[mb][nb], 0, 0, 0);
  }

  if (z < 2) {
    _Float16* op = (z == 0 ? Qs : Ks) + (size_t)bz * NN * CC;
#pragma unroll
    for (int mb = 0; mb < 4; mb++) {
      int d0 = m0 + wm + mb * 16 + quad * 4;
      float b0 = bias[d0], b1 = bias[d0 + 1], b2 = bias[d0 + 2], b3 = bias[d0 + 3];
      const int cs = d0 >> 4, hh = (d0 >> 3) & 1, j0 = d0 & 7;
#pragma unroll
      for (int nb = 0; nb < 4; nb++) {
        int n_ = n0 + wn + nb * 16 + l15;
        int kt = n_ >> 5, ql_ = n_ & 31;
        half4 pk;
        pk[0] = (_Float16)(acc[mb][nb][0] + b0);
        pk[1] = (_Float16)(acc[mb][nb][1] + b1);
        pk[2] = (_Float16)(acc[mb][nb][2] + b2);
        pk[3] = (_Float16)(acc[mb][nb][3] + b3);
        size_t idx = ((size_t)(kt * 16 + cs) * 64 + ql_ + 32 * hh) * 8 + j0;
        *(half4*)(op + idx) = pk;
      }
    }
  } else {
    _Float16* op = Vs + (size_t)bz * NN * CC;
#pragma unroll
    for (int mb = 0; mb < 4; mb++) {
      int nq0 = m0 + wm + mb * 16 + quad * 4;
      const int kt = nq0 >> 5, krel = nq0 & 31;
      const int hk = krel >> 4, hh = (krel >> 3) & 1, j0 = krel & 7;
#pragma unroll
      for (int nb = 0; nb < 4; nb++) {
        int d = n0 + wn + nb * 16 + l15;
        int ql_ = d & 31, g = (d >> 5) & 7;
        float bv = bias[d];
        half4 pk;
        pk[0] = (_Float16)(acc[mb][nb][0] + bv);
        pk[1] = (_Float16)(acc[mb][nb][1] + bv);
        pk[2] = (_Float16)(acc[mb][nb][2] + bv);
        pk[3] = (_Float16)(acc[mb][nb][3] + bv);
        size_t idx = (((size_t)(kt * 8 + g) * 2 + hk) * 64 + ql_ + 32 * hh) * 8 + j0;
        *(half4*)(op + idx) = pk;
      }
    }
  }
}

// ---------------------------------------------------------------------------
// Flash attention v9 (R1-exact, harness-verified): global_load_lds K/V dbuf,
// 1 barrier/iter, in-register P via cvt_pk+permlane32_swap (DISTINCT operands
// only — R3 pitfall), setprio. Stagger removed (R4: neutral).
// grid (32 qtiles, 4 chunks, NB), 256 threads.
// ---------------------------------------------------------------------------
__global__ __launch_bounds__(256, 2) void k_attn(const _Float16* __restrict__ Q,
                                                 const _Float16* __restrict__ K,
                                                 const _Float16* __restrict__ Vt,
                                                 _Float16* __restrict__ Opart,
                                                 float2* __restrict__ Ml) {
  __shared__ _Float16 smem[8192 * 4];  // K dbuf 32KB | V dbuf 32KB
  const int tid = threadIdx.x;
  const int wave = tid >> 6, lane = tid & 63;

  const int qt = blockIdx.x, ck = blockIdx.y, b = blockIdx.z;
  const int ql = lane & 31, h = lane >> 5;
  const int q0 = qt * 128 + wave * 32;
  const _Float16* Qb = Q + (size_t)b * NN * CC;
  const _Float16* Kg = K + (size_t)b * NN * CC;
  const _Float16* Vg = Vt + (size_t)b * NN * CC;
  const int kt_base = ck * KITERS;
  const int so = wave * 512;             // per-wave LDS stage base (halves)
  const int go = wave * 512 + lane * 8;  // per-lane global offset (halves)

  const int ktq = q0 >> 5;
  half8 qf[16];
#pragma unroll
  for (int cs = 0; cs < 16; cs++)
    qf[cs] = *(const half8*)(Qb + ((size_t)(ktq * 16 + cs) * 64 + lane) * 8);

  float16v Oa[8];
#pragma unroll
  for (int g = 0; g < 8; g++)
#pragma unroll
    for (int i = 0; i < 16; i++) Oa[g][i] = 0.f;

  float m_run = -1e30f, l_run = 0.f;
  half8 pf0, pf1;  // previous-iter P fragments, live in registers
#pragma unroll
  for (int i = 0; i < 8; i++) { pf0[i] = (_Float16)0.f; pf1[i] = (_Float16)0.f; }

  // prologue: stage K[0] -> Kbuf0
  {
    const _Float16* Kt = Kg + (size_t)kt_base * 8192;
#pragma unroll
    for (int p = 0; p < 4; p++) a16(Kt + p * 2048 + go, smem + p * 2048 + so);
  }

  for (int t = 0; t < KITERS; t++) {
    asm volatile("s_waitcnt vmcnt(0)" ::: "memory");  // K[t] (+V[t-1]) landed
    __builtin_amdgcn_s_barrier();
    // stage V[t] -> Vbuf[t&1]; K[t+1] -> Kbuf[(t+1)&1]
    {
      const _Float16* Vtile = Vg + (size_t)(kt_base + t) * 8192;
      _Float16* Vw = smem + (2 + (t & 1)) * 8192;
#pragma unroll
      for (int p = 0; p < 4; p++) a16(Vtile + p * 2048 + go, Vw + p * 2048 + so);
      if (t + 1 < KITERS) {
        const _Float16* Kt = Kg + (size_t)(kt_base + t + 1) * 8192;
        _Float16* Kw = smem + ((t + 1) & 1) * 8192;
#pragma unroll
        for (int p = 0; p < 4; p++) a16(Kt + p * 2048 + go, Kw + p * 2048 + so);
      }
    }
    const _Float16* Kl = smem + (t & 1) * 8192;

    // ---- MFMA burst: S_i and PV_i interleaved; PV in ks-outer order:
    //   i<8: Oa[i]   += V[2i]  ·pf0     i>=8: Oa[i-8] += V[2(i-8)+1]·pf1
    float16v s, s2;
#pragma unroll
    for (int i = 0; i < 16; i++) { s[i] = 0.f; s2[i] = 0.f; }
    __builtin_amdgcn_s_setprio(1);
    if (t > 0) {
      const _Float16* Vr = smem + (2 + ((t - 1) & 1)) * 8192;
#pragma unroll
      for (int i = 0; i < 16; i++) {
        half8 kf = *(const half8*)(Kl + i * 512 + lane * 8);
        if (i & 1)
          s2 = __builtin_amdgcn_mfma_f32_32x32x16_f16(kf, qf[i], s2, 0, 0, 0);
        else
          s = __builtin_amdgcn_mfma_f32_32x32x16_f16(kf, qf[i], s, 0, 0, 0);
        const int u = i & 7, ks = i >> 3;
        half8 vf = *(const half8*)(Vr + (2 * u + ks) * 512 + lane * 8);
        Oa[u] = __builtin_amdgcn_mfma_f32_32x32x16_f16(vf, ks ? pf1 : pf0, Oa[u], 0, 0, 0);
      }
    } else {
#pragma unroll
      for (int cs = 0; cs < 16; cs += 2) {
        half8 kfa = *(const half8*)(Kl + cs * 512 + lane * 8);
        s = __builtin_amdgcn_mfma_f32_32x32x16_f16(kfa, qf[cs], s, 0, 0, 0);
        half8 kfb = *(const half8*)(Kl + (cs + 1) * 512 + lane * 8);
        s2 = __builtin_amdgcn_mfma_f32_32x32x16_f16(kfb, qf[cs + 1], s2, 0, 0, 0);
      }
    }
    __builtin_amdgcn_s_setprio(0);
#pragma unroll
    for (int i = 0; i < 16; i++) s[i] += s2[i];

    // ---- lazy online softmax (per-lane), tree reductions
    float t0 = fmaxf(s[0], s[1]), t1 = fmaxf(s[2], s[3]);
    float t2 = fmaxf(s[4], s[5]), t3 = fmaxf(s[6], s[7]);
    float t4 = fmaxf(s[8], s[9]), t5 = fmaxf(s[10], s[11]);
    float t6 = fmaxf(s[12], s[13]), t7 = fmaxf(s[14], s[15]);
    t0 = fmaxf(t0, t1); t2 = fmaxf(t2, t3); t4 = fmaxf(t4, t5); t6 = fmaxf(t6, t7);
    float tmax = fmaxf(fmaxf(t0, t2), fmaxf(t4, t6));
    tmax = fmaxf(tmax, __shfl_xor(tmax, 32));
    bool need = tmax > m_run + 8.0f;
    if (__any((int)need)) {
      float mN = need ? tmax : m_run;
      float alpha = __expf(m_run - mN);
      m_run = mN;
      l_run *= alpha;
#pragma unroll
      for (int g = 0; g < 8; g++)
#pragma unroll
        for (int i = 0; i < 16; i++) Oa[g][i] *= alpha;
    }
#pragma unroll
    for (int i = 0; i < 16; i++) s[i] = __expf(s[i] - m_run);
    float u0 = (s[0] + s[1]) + (s[2] + s[3]);
    float u1 = (s[4] + s[5]) + (s[6] + s[7]);
    float u2 = (s[8] + s[9]) + (s[10] + s[11]);
    float u3 = (s[12] + s[13]) + (s[14] + s[15]);
    float ts = (u0 + u1) + (u2 + u3);
    ts += __shfl_xor(ts, 32);
    l_run += ts;

    // ---- P -> registers: pack f16 pairs, swap halves across lane 32 boundary.
    {
      int A01 = packh2(s[0], s[1]), B23 = packh2(s[2], s[3]);
      int C45 = packh2(s[4], s[5]), D67 = packh2(s[6], s[7]);
      int E01 = packh2(s[8], s[9]), F23 = packh2(s[10], s[11]);
      int G45 = packh2(s[12], s[13]), H67 = packh2(s[14], s[15]);
      auto rA = __builtin_amdgcn_permlane32_swap(A01, C45, false, false);
      auto rB = __builtin_amdgcn_permlane32_swap(B23, D67, false, false);
      auto rC = __builtin_amdgcn_permlane32_swap(E01, G45, false, false);
      auto rD = __builtin_amdgcn_permlane32_swap(F23, H67, false, false);
      intx4 w0, w1;
      w0[0] = rA[0]; w0[1] = rB[0]; w0[2] = rA[1]; w0[3] = rB[1];
      w1[0] = rC[0]; w1[1] = rD[0]; w1[2] = rC[1]; w1[3] = rD[1];
      pf0 = __builtin_bit_cast(half8, w0);
      pf1 = __builtin_bit_cast(half8, w1);
    }
  }

  // ---- tail: PV for last tile (ks-outer, same per-chain order)
  asm volatile("s_waitcnt vmcnt(0)" ::: "memory");  // V[KITERS-1] landed
  __builtin_amdgcn_s_barrier();
  {
    const _Float16* Vr = smem + (2 + ((KITERS - 1) & 1)) * 8192;
#pragma unroll
    for (int u = 0; u < 8; u++) {
      half8 vfa = *(const half8*)(Vr + (2 * u) * 512 + lane * 8);
      Oa[u] = __builtin_amdgcn_mfma_f32_32x32x16_f16(vfa, pf0, Oa[u], 0, 0, 0);
    }
#pragma unroll
    for (int u = 0; u < 8; u++) {
      half8 vfb = *(const half8*)(Vr + (2 * u + 1) * 512 + lane * 8);
      Oa[u] = __builtin_amdgcn_mfma_f32_32x32x16_f16(vfb, pf1, Oa[u], 0, 0, 0);
    }
  }

  // ---- epilogue: normalize, per-wave LDS transpose, coalesced store
  float invl = 1.f / l_run;
  __syncthreads();
  float* ot = (float*)smem + wave * (32 * 33);
  _Float16* Opb = Opart + ((size_t)ck * NB + b) * NN * CC;
  const int qr = lane >> 1;
  const int chalf = (lane & 1) * 16;
#pragma unroll
  for (int g = 0; g < 8; g++) {
#pragma unroll
    for (int r = 0; r < 16; r++)
      ot[((r & 3) + 8 * (r >> 2) + 4 * h) * 33 + ql] = Oa[g][r] * invl;
    __builtin_amdgcn_s_waitcnt(WAIT_LGKM0);
    half8 o0, o1;
#pragma unroll
    for (int i = 0; i < 8; i++) o0[i] = (_Float16)ot[(chalf + i) * 33 + qr];
#pragma unroll
    for (int i = 0; i < 8; i++) o1[i] = (_Float16)ot[(chalf + 8 + i) * 33 + qr];
    _Float16* gp = Opb + (size_t)(q0 + qr) * CC + g * 32 + chalf;
    *(half8*)gp = o0;
    *(half8*)(gp + 8) = o1;
    __builtin_amdgcn_s_waitcnt(WAIT_LGKM0);
  }
  if (h == 0) {
    float2 ml; ml.x = m_run; ml.y = l_run;
    Ml[((size_t)ck * NB + b) * NN + q0 + ql] = ml;
  }
}

// ---------------------------------------------------------------------------
// Final conv with fused split-K merge. v16 = R6's K-step-64 (2 blocks/CU,
// light VGPR) + raw lgkm-only barriers + prefetch issued BEFORE barrier 1.
// PITFALL (R7): __syncthreads drains vmcnt(0) — a prefetch issued before it
// becomes a synchronous stall. Raw `s_waitcnt lgkmcnt(0); s_barrier` orders
// the LDS hazards (own frag-reads done before overwrite / own writes flushed
// before cross-wave read) while vmcnt stays untouched, so the Opart/Wo loads
// remain in flight across writes + barrier + 16 MFMA and drain only at the
// next iteration's merge. Load reordering is value-neutral -> bit-exact.
// out[b][d][n] fp32 = Wo . O^T + bo. grid (128, NB), 256 thr, 27.6 KB LDS.
// ---------------------------------------------------------------------------
__global__ __launch_bounds__(256, 2) void k_out(const _Float16* __restrict__ Opart,
                                                const float2* __restrict__ Ml,
                                                const float* __restrict__ Wo,
                                                const float* __restrict__ bo,
                                                float* __restrict__ out) {
  __shared__ _Float16 As[64][72];    // 9 KB   (merged O rows, 64-c slice)
  __shared__ _Float16 Bs[128][72];   // 18 KB  (Wo rows, 64-c slice)
  const int bz = blockIdx.y;
  const int mt = blockIdx.x >> 1, nt = blockIdx.x & 1;  // 64 mtiles x 2 ntiles
  const int m0 = mt * 64, n0 = nt * 128;
  const int tid = threadIdx.x;
  const int wave = tid >> 6, lane = tid & 63, quad = lane >> 4, l15 = lane & 15;
  const int wn = wave * 32;

  floatx4 acc[4][2];
#pragma unroll
  for (int i = 0; i < 4; i++)
#pragma unroll
    for (int j = 0; j < 2; j++) acc[i][j] = (floatx4){0.f, 0.f, 0.f, 0.f};

  const int arow = tid >> 2, acol = (tid & 3) * 16;   // A: 64 rows x 64 c
  const int brow = tid >> 1, bcol = (tid & 1) * 32;   // B: 128 rows x 64 c

  // merge weights for this thread's fixed row q = m0 + arow
  const size_t qi = (size_t)bz * NN + m0 + arow;
  float2 a0 = Ml[qi], a1 = Ml[(size_t)NB * NN + qi];
  float2 a2 = Ml[(size_t)2 * NB * NN + qi], a3 = Ml[(size_t)3 * NB * NN + qi];
  float M = fmaxf(fmaxf(a0.x, a1.x), fmaxf(a2.x, a3.x));
  float w0 = __expf(a0.x - M) * a0.y, w1 = __expf(a1.x - M) * a1.y;
  float w2 = __expf(a2.x - M) * a2.y, w3 = __expf(a3.x - M) * a3.y;
  float inv = 1.f / (w0 + w1 + w2 + w3);
  w0 *= inv; w1 *= inv; w2 *= inv; w3 *= inv;
  const size_t ps = (size_t)NB * NN * CC;
  const _Float16* prow = Opart + qi * CC;

  // preload kk=0: 4 planes x 2 half-slices of O, 8 float4 of Wo
  half8 pA[4][2];
  float4 wr[8];
  {
    const _Float16* pr = prow + acol;
#pragma unroll
    for (int pl = 0; pl < 4; pl++) {
      pA[pl][0] = *(const half8*)(pr + (size_t)pl * ps);
      pA[pl][1] = *(const half8*)(pr + (size_t)pl * ps + 8);
    }
    const float4* wp = (const float4*)(Wo + (size_t)(n0 + brow) * 256 + bcol);
#pragma unroll
    for (int i = 0; i < 8; i++) wr[i] = wp[i];
  }

  for (int kk = 0; kk < 256; kk += 64) {
    half8 ma0, ma1;
#pragma unroll
    for (int i = 0; i < 8; i++) {
      ma0[i] = (_Float16)(w0 * (float)pA[0][0][i] + w1 * (float)pA[1][0][i] +
                          w2 * (float)pA[2][0][i] + w3 * (float)pA[3][0][i]);
      ma1[i] = (_Float16)(w0 * (float)pA[0][1][i] + w1 * (float)pA[1][1][i] +
                          w2 * (float)pA[2][1][i] + w3 * (float)pA[3][1][i]);
    }
    half8 bl0, bh0, bl1, bh1;
    cvt16v(wr[0], wr[1], wr[2], wr[3], bl0, bh0);
    cvt16v(wr[4], wr[5], wr[6], wr[7], bl1, bh1);
    // EARLY prefetch: regs are free after merge/cvt; with raw lgkm barriers
    // below, these loads stay in flight across the whole iteration.
    if (kk + 64 < 256) {
      const _Float16* pr = prow + kk + 64 + acol;
#pragma unroll
      for (int pl = 0; pl < 4; pl++) {
        pA[pl][0] = *(const half8*)(pr + (size_t)pl * ps);
        pA[pl][1] = *(const half8*)(pr + (size_t)pl * ps + 8);
      }
      const float4* wp = (const float4*)(Wo + (size_t)(n0 + brow) * 256 + kk + 64 + bcol);
#pragma unroll
      for (int i = 0; i < 8; i++) wr[i] = wp[i];
    }
    // barrier 1: own frag ds_reads (prev MFMA phase) done before overwrite
    asm volatile("s_waitcnt lgkmcnt(0)" ::: "memory");
    asm volatile("s_barrier" ::: "memory");
    *(half8*)&As[arow][acol] = ma0;
    *(half8*)&As[arow][acol + 8] = ma1;
    *(half8*)&Bs[brow][bcol] = bl0;
    *(half8*)&Bs[brow][bcol + 8] = bh0;
    *(half8*)&Bs[brow][bcol + 16] = bl1;
    *(half8*)&Bs[brow][bcol + 24] = bh1;
    // barrier 2: own ds_writes flushed; tiles visible to all waves
    asm volatile("s_waitcnt lgkmcnt(0)" ::: "memory");
    asm volatile("s_barrier" ::: "memory");
#pragma unroll
    for (int ks = 0; ks < 2; ks++) {
      half8 af[4], bfr[2];
#pragma unroll
      for (int mb = 0; mb < 4; mb++)
        af[mb] = *(const half8*)&As[mb * 16 + l15][ks * 32 + quad * 8];
#pragma unroll
      for (int nb = 0; nb < 2; nb++)
        bfr[nb] = *(const half8*)&Bs[wn + nb * 16 + l15][ks * 32 + quad * 8];
#pragma unroll
      for (int mb = 0; mb < 4; mb++)
#pragma unroll
        for (int nb = 0; nb < 2; nb++)
          acc[mb][nb] = __builtin_amdgcn_mfma_f32_16x16x32_f16(af[mb], bfr[nb], acc[mb][nb], 0, 0, 0);
    }
  }

  float* op = out + (size_t)bz * NN * CC;
#pragma unroll
  for (int mb = 0; mb < 4; mb++) {
    int nq0 = m0 + mb * 16 + quad * 4;  // spatial
#pragma unroll
    for (int nb = 0; nb < 2; nb++) {
      int d = n0 + wn + nb * 16 + l15;
      float bv = bo[d];
      floatx4 pk;
      pk[0] = acc[mb][nb][0] + bv;
      pk[1] = acc[mb][nb][1] + bv;
      pk[2] = acc[mb][nb][2] + bv;
      pk[3] = acc[mb][nb][3] + bv;
      *(floatx4*)(op + (size_t)d * NN + nq0) = pk;
    }
  }
}

// ---------------------------------------------------------------------------
extern "C" void kernel_launch(void* const* d_in, const int* in_sizes, int n_in,
                              void* d_out, int out_size, void* d_ws, size_t ws_size,
                              hipStream_t stream) {
  const float* Fc = (const float*)d_in[0];
  const float* Fs = (const float*)d_in[1];
  const float* Wf = (const float*)d_in[2];
  const float* bf_ = (const float*)d_in[3];
  const float* Wg = (const float*)d_in[4];
  const float* bg = (const float*)d_in[5];
  const float* Wh = (const float*)d_in[6];
  const float* bh = (const float*)d_in[7];
  const float* Wo = (const float*)d_in[8];
  const float* bo = (const float*)d_in[9];

  char* ws = (char*)d_ws;
  const size_t sz = (size_t)NB * NN * CC * sizeof(_Float16);  // 8 MB per plane
  _Float16* Opart = (_Float16*)(ws + 0 * sz);  // planes 0..3 (split-K partials)
  _Float16* Qs = (_Float16*)(ws + 4 * sz);     // swizzled
  _Float16* Ks = (_Float16*)(ws + 5 * sz);
  _Float16* Vs = (_Float16*)(ws + 6 * sz);
  float2* Ml = (float2*)(ws + 7 * sz);         // 512 KB

  k_qkv<<<dim3(64, NB, 3), 256, 0, stream>>>(Fc, Fs, Wf, Wg, Wh, bf_, bg, bh, Qs, Ks, Vs);
  k_attn<<<dim3(32, 4, NB), 256, 0, stream>>>(Qs, Ks, Vs, Opart, Ml);
  k_out<<<dim3(128, NB), 256, 0, stream>>>(Opart, Ml, Wo, bo, (float*)d_out);
}

// Round 9
// 200.235 us; speedup vs baseline: 1.0133x; 1.0113x over previous
//
#include <hip/hip_runtime.h>
#include <stdint.h>

#define NB 4
#define CC 256
#define NN 4096   // H*W = 64*64
#define KITERS 32 // k-steps per attention chunk (chunk = 1024)
#define WAIT_LGKM0 0xC07F  // s_waitcnt lgkmcnt(0), vmcnt/expcnt untouched

typedef __attribute__((ext_vector_type(8))) _Float16 half8;   // MFMA A/B frag (4 VGPR)
typedef __attribute__((ext_vector_type(4))) _Float16 half4;   // 8B packed store
typedef __attribute__((ext_vector_type(2))) _Float16 half2v;
typedef __attribute__((ext_vector_type(4))) float floatx4;    // 16x16 acc
typedef __attribute__((ext_vector_type(16))) float float16v;  // 32x32 acc
typedef __attribute__((ext_vector_type(4))) int intx4;        // 16B copy

__device__ __forceinline__ void cvt16v(float4 a, float4 b, float4 c, float4 d,
                                       half8& lo, half8& hi) {
  lo[0] = (_Float16)a.x; lo[1] = (_Float16)a.y; lo[2] = (_Float16)a.z; lo[3] = (_Float16)a.w;
  lo[4] = (_Float16)b.x; lo[5] = (_Float16)b.y; lo[6] = (_Float16)b.z; lo[7] = (_Float16)b.w;
  hi[0] = (_Float16)c.x; hi[1] = (_Float16)c.y; hi[2] = (_Float16)c.z; hi[3] = (_Float16)c.w;
  hi[4] = (_Float16)d.x; hi[5] = (_Float16)d.y; hi[6] = (_Float16)d.z; hi[7] = (_Float16)d.w;
}

// pack two f32 -> one u32 of two f16 (RTE, identical to scalar casts)
__device__ __forceinline__ int packh2(float a, float b) {
  half2v p; p[0] = (_Float16)a; p[1] = (_Float16)b;
  return __builtin_bit_cast(int, p);
}

// async global->LDS, 16B per lane; lds dest = wave-uniform base + lane*16.
// PROVEN FORM (R1/R4): global side cast via uintptr, LDS side cast DIRECTLY
// from the generic pointer. PITFALL (R2): LDS side via uintptr_t reinterprets
// the FLAT address as an LDS offset -> garbage.
__device__ __forceinline__ void a16(const _Float16* g, _Float16* l) {
  __builtin_amdgcn_global_load_lds(
      (__attribute__((address_space(1))) void*)(uintptr_t)g,
      (__attribute__((address_space(3))) void*)l, 16, 0, 0);
}

// ---------------------------------------------------------------------------
// Fused transpose + Q/KV projections -> FRAG-MAJOR (swizzled) outputs. v17:
// z=0: Q = Wf.Fc (as before). z=1: K = Wg.Fs AND Vt = (Fs^T.Wh^T)^T FUSED —
// the Fs tile is staged + transposed ONCE and feeds both products (the
// separate K and V blocks previously duplicated all F staging + transpose
// + 16 scalar ds_reads/thread/iter + 16MB of Fs HBM reads).
// Same 3-barrier skeleton as the proven R1 kernel; K/V writers identical to
// the old z=1/z=2 writers (same geometry decode). Bit-exact.
// grid (64, NB, 2), 256 threads, 2 blocks/CU (46.9 KB LDS, ~230 VGPR).
// ---------------------------------------------------------------------------
__global__ __launch_bounds__(256, 2) void k_qkv(const float* __restrict__ Fc,
                                                const float* __restrict__ Fs,
                                                const float* __restrict__ Wf,
                                                const float* __restrict__ Wg,
                                                const float* __restrict__ Wh,
                                                const float* __restrict__ bf,
                                                const float* __restrict__ bg,
                                                const float* __restrict__ bh,
                                                _Float16* __restrict__ Qs,
                                                _Float16* __restrict__ Ks,
                                                _Float16* __restrict__ Vs) {
  __shared__ float tmp[32][132];     // 16.9 KB fp32 transpose staging
  __shared__ _Float16 Gs[128][40];   // 10 KB: Wf (z=0) or Wg (z=1)
  __shared__ _Float16 Hs[128][40];   // 10 KB: Wh (z=1 only)
  __shared__ _Float16 Xs[128][40];   // 10 KB: F^T slice (n x c)
  const int z = blockIdx.z, bz = blockIdx.y;
  const float* F = ((z == 0) ? Fc : Fs) + (size_t)bz * CC * NN;
  const float* W1 = (z == 0) ? Wf : Wg;
  const int dblk = blockIdx.x >> 5, nblk = blockIdx.x & 31;
  const int wd0 = dblk * 128;   // W row base (channel side)
  const int xn0 = nblk * 128;   // spatial base of the F tile
  const int tid = threadIdx.x;
  const int wave = tid >> 6, lane = tid & 63, quad = lane >> 4, l15 = lane & 15;
  const int wm = (wave >> 1) * 64, wn = (wave & 1) * 64;

  floatx4 acck[4][4];  // Q (z=0) or K (z=1)
  floatx4 accv[4][4];  // V (z=1 only)
#pragma unroll
  for (int i = 0; i < 4; i++)
#pragma unroll
    for (int j = 0; j < 4; j++) {
      acck[i][j] = (floatx4){0.f, 0.f, 0.f, 0.f};
      accv[i][j] = (floatx4){0.f, 0.f, 0.f, 0.f};
    }

  const int srow = tid >> 1, shalf = (tid & 1) * 16;   // W staging
  const int fc = tid >> 3, fn = (tid & 7) * 16;        // F load (c-row, n-off)
  const int xr = tid >> 1, xh = (tid & 1) * 16;        // transposed read

  float4 wg0, wg1, wg2, wg3, wh0, wh1, wh2, wh3, fr0, fr1, fr2, fr3;
  {
    const float4* wp = (const float4*)(W1 + (size_t)(wd0 + srow) * 256 + 0 + shalf);
    wg0 = wp[0]; wg1 = wp[1]; wg2 = wp[2]; wg3 = wp[3];
    if (z) {
      const float4* hp = (const float4*)(Wh + (size_t)(wd0 + srow) * 256 + 0 + shalf);
      wh0 = hp[0]; wh1 = hp[1]; wh2 = hp[2]; wh3 = hp[3];
    }
    const float4* fp = (const float4*)(F + (size_t)(0 + fc) * NN + xn0 + fn);
    fr0 = fp[0]; fr1 = fp[1]; fr2 = fp[2]; fr3 = fp[3];
  }

  for (int kk = 0; kk < 256; kk += 32) {
    __syncthreads();  // 1: prev frag+tmp reads done
    *(float4*)&tmp[fc][fn + 0] = fr0;
    *(float4*)&tmp[fc][fn + 4] = fr1;
    *(float4*)&tmp[fc][fn + 8] = fr2;
    *(float4*)&tmp[fc][fn + 12] = fr3;
    {
      half8 w_lo, w_hi;
      cvt16v(wg0, wg1, wg2, wg3, w_lo, w_hi);
      *(half8*)&Gs[srow][shalf] = w_lo;
      *(half8*)&Gs[srow][shalf + 8] = w_hi;
      if (z) {
        half8 h_lo, h_hi;
        cvt16v(wh0, wh1, wh2, wh3, h_lo, h_hi);
        *(half8*)&Hs[srow][shalf] = h_lo;
        *(half8*)&Hs[srow][shalf + 8] = h_hi;
      }
    }
    __syncthreads();  // 2: tmp + W-side visible
    if (kk + 32 < 256) {  // prefetch next iter
      const float4* wp = (const float4*)(W1 + (size_t)(wd0 + srow) * 256 + kk + 32 + shalf);
      wg0 = wp[0]; wg1 = wp[1]; wg2 = wp[2]; wg3 = wp[3];
      if (z) {
        const float4* hp = (const float4*)(Wh + (size_t)(wd0 + srow) * 256 + kk + 32 + shalf);
        wh0 = hp[0]; wh1 = hp[1]; wh2 = hp[2]; wh3 = hp[3];
      }
      const float4* fp = (const float4*)(F + (size_t)(kk + 32 + fc) * NN + xn0 + fn);
      fr0 = fp[0]; fr1 = fp[1]; fr2 = fp[2]; fr3 = fp[3];
    }
    half8 xlo, xhi;
#pragma unroll
    for (int i = 0; i < 8; i++) xlo[i] = (_Float16)tmp[xh + i][xr];
#pragma unroll
    for (int i = 0; i < 8; i++) xhi[i] = (_Float16)tmp[xh + 8 + i][xr];
    *(half8*)&Xs[xr][xh] = xlo;
    *(half8*)&Xs[xr][xh + 8] = xhi;
    __syncthreads();  // 3: Gs/Hs/Xs complete
    {
      half8 af[4], bfr[4];
#pragma unroll
      for (int mb = 0; mb < 4; mb++) af[mb] = *(const half8*)&Gs[wm + mb * 16 + l15][quad * 8];
#pragma unroll
      for (int nb = 0; nb < 4; nb++) bfr[nb] = *(const half8*)&Xs[wn + nb * 16 + l15][quad * 8];
#pragma unroll
      for (int mb = 0; mb < 4; mb++)
#pragma unroll
        for (int nb = 0; nb < 4; nb++)
          acck[mb][nb] = __builtin_amdgcn_mfma_f32_16x16x32_f16(af[mb], bfr[nb], acck[mb][nb], 0, 0, 0);
    }
    if (z) {
      half8 av[4], bv[4];
#pragma unroll
      for (int mb = 0; mb < 4; mb++) av[mb] = *(const half8*)&Xs[wm + mb * 16 + l15][quad * 8];
#pragma unroll
      for (int nb = 0; nb < 4; nb++) bv[nb] = *(const half8*)&Hs[wn + nb * 16 + l15][quad * 8];
#pragma unroll
      for (int mb = 0; mb < 4; mb++)
#pragma unroll
        for (int nb = 0; nb < 4; nb++)
          accv[mb][nb] = __builtin_amdgcn_mfma_f32_16x16x32_f16(av[mb], bv[nb], accv[mb][nb], 0, 0, 0);
    }
  }

  {  // Q/K writer (old z<2 writer with m0:=wd0, n0:=xn0)
    const float* bias = (z == 0) ? bf : bg;
    _Float16* op = (z == 0 ? Qs : Ks) + (size_t)bz * NN * CC;
#pragma unroll
    for (int mb = 0; mb < 4; mb++) {
      int d0 = wd0 + wm + mb * 16 + quad * 4;
      float b0 = bias[d0], b1 = bias[d0 + 1], b2 = bias[d0 + 2], b3 = bias[d0 + 3];
      const int cs = d0 >> 4, hh = (d0 >> 3) & 1, j0 = d0 & 7;
#pragma unroll
      for (int nb = 0; nb < 4; nb++) {
        int n_ = xn0 + wn + nb * 16 + l15;
        int kt = n_ >> 5, ql_ = n_ & 31;
        half4 pk;
        pk[0] = (_Float16)(acck[mb][nb][0] + b0);
        pk[1] = (_Float16)(acck[mb][nb][1] + b1);
        pk[2] = (_Float16)(acck[mb][nb][2] + b2);
        pk[3] = (_Float16)(acck[mb][nb][3] + b3);
        size_t idx = ((size_t)(kt * 16 + cs) * 64 + ql_ + 32 * hh) * 8 + j0;
        *(half4*)(op + idx) = pk;
      }
    }
  }
  if (z) {  // V writer (old z=2 writer with m0:=xn0, n0:=wd0)
    _Float16* op = Vs + (size_t)bz * NN * CC;
#pragma unroll
    for (int mb = 0; mb < 4; mb++) {
      int nq0 = xn0 + wm + mb * 16 + quad * 4;
      const int kt = nq0 >> 5, krel = nq0 & 31;
      const int hk = krel >> 4, hh = (krel >> 3) & 1, j0 = krel & 7;
#pragma unroll
      for (int nb = 0; nb < 4; nb++) {
        int d = wd0 + wn + nb * 16 + l15;
        int ql_ = d & 31, g = (d >> 5) & 7;
        float bv2 = bh[d];
        half4 pk;
        pk[0] = (_Float16)(accv[mb][nb][0] + bv2);
        pk[1] = (_Float16)(accv[mb][nb][1] + bv2);
        pk[2] = (_Float16)(accv[mb][nb][2] + bv2);
        pk[3] = (_Float16)(accv[mb][nb][3] + bv2);
        size_t idx = (((size_t)(kt * 8 + g) * 2 + hk) * 64 + ql_ + 32 * hh) * 8 + j0;
        *(half4*)(op + idx) = pk;
      }
    }
  }
}

// ---------------------------------------------------------------------------
// Flash attention v9 (R1-exact, harness-verified): global_load_lds K/V dbuf,
// 1 barrier/iter, in-register P via cvt_pk+permlane32_swap (DISTINCT operands
// only — R3 pitfall), setprio. grid (32 qtiles, 4 chunks, NB), 256 threads.
// ---------------------------------------------------------------------------
__global__ __launch_bounds__(256, 2) void k_attn(const _Float16* __restrict__ Q,
                                                 const _Float16* __restrict__ K,
                                                 const _Float16* __restrict__ Vt,
                                                 _Float16* __restrict__ Opart,
                                                 float2* __restrict__ Ml) {
  __shared__ _Float16 smem[8192 * 4];  // K dbuf 32KB | V dbuf 32KB
  const int tid = threadIdx.x;
  const int wave = tid >> 6, lane = tid & 63;

  const int qt = blockIdx.x, ck = blockIdx.y, b = blockIdx.z;
  const int ql = lane & 31, h = lane >> 5;
  const int q0 = qt * 128 + wave * 32;
  const _Float16* Qb = Q + (size_t)b * NN * CC;
  const _Float16* Kg = K + (size_t)b * NN * CC;
  const _Float16* Vg = Vt + (size_t)b * NN * CC;
  const int kt_base = ck * KITERS;
  const int so = wave * 512;             // per-wave LDS stage base (halves)
  const int go = wave * 512 + lane * 8;  // per-lane global offset (halves)

  const int ktq = q0 >> 5;
  half8 qf[16];
#pragma unroll
  for (int cs = 0; cs < 16; cs++)
    qf[cs] = *(const half8*)(Qb + ((size_t)(ktq * 16 + cs) * 64 + lane) * 8);

  float16v Oa[8];
#pragma unroll
  for (int g = 0; g < 8; g++)
#pragma unroll
    for (int i = 0; i < 16; i++) Oa[g][i] = 0.f;

  float m_run = -1e30f, l_run = 0.f;
  half8 pf0, pf1;  // previous-iter P fragments, live in registers
#pragma unroll
  for (int i = 0; i < 8; i++) { pf0[i] = (_Float16)0.f; pf1[i] = (_Float16)0.f; }

  // prologue: stage K[0] -> Kbuf0
  {
    const _Float16* Kt = Kg + (size_t)kt_base * 8192;
#pragma unroll
    for (int p = 0; p < 4; p++) a16(Kt + p * 2048 + go, smem + p * 2048 + so);
  }

  for (int t = 0; t < KITERS; t++) {
    asm volatile("s_waitcnt vmcnt(0)" ::: "memory");  // K[t] (+V[t-1]) landed
    __builtin_amdgcn_s_barrier();
    // stage V[t] -> Vbuf[t&1]; K[t+1] -> Kbuf[(t+1)&1]
    {
      const _Float16* Vtile = Vg + (size_t)(kt_base + t) * 8192;
      _Float16* Vw = smem + (2 + (t & 1)) * 8192;
#pragma unroll
      for (int p = 0; p < 4; p++) a16(Vtile + p * 2048 + go, Vw + p * 2048 + so);
      if (t + 1 < KITERS) {
        const _Float16* Kt = Kg + (size_t)(kt_base + t + 1) * 8192;
        _Float16* Kw = smem + ((t + 1) & 1) * 8192;
#pragma unroll
        for (int p = 0; p < 4; p++) a16(Kt + p * 2048 + go, Kw + p * 2048 + so);
      }
    }
    const _Float16* Kl = smem + (t & 1) * 8192;

    // ---- MFMA burst: S_i and PV_i interleaved; PV in ks-outer order:
    //   i<8: Oa[i]   += V[2i]  ·pf0     i>=8: Oa[i-8] += V[2(i-8)+1]·pf1
    float16v s, s2;
#pragma unroll
    for (int i = 0; i < 16; i++) { s[i] = 0.f; s2[i] = 0.f; }
    __builtin_amdgcn_s_setprio(1);
    if (t > 0) {
      const _Float16* Vr = smem + (2 + ((t - 1) & 1)) * 8192;
#pragma unroll
      for (int i = 0; i < 16; i++) {
        half8 kf = *(const half8*)(Kl + i * 512 + lane * 8);
        if (i & 1)
          s2 = __builtin_amdgcn_mfma_f32_32x32x16_f16(kf, qf[i], s2, 0, 0, 0);
        else
          s = __builtin_amdgcn_mfma_f32_32x32x16_f16(kf, qf[i], s, 0, 0, 0);
        const int u = i & 7, ks = i >> 3;
        half8 vf = *(const half8*)(Vr + (2 * u + ks) * 512 + lane * 8);
        Oa[u] = __builtin_amdgcn_mfma_f32_32x32x16_f16(vf, ks ? pf1 : pf0, Oa[u], 0, 0, 0);
      }
    } else {
#pragma unroll
      for (int cs = 0; cs < 16; cs += 2) {
        half8 kfa = *(const half8*)(Kl + cs * 512 + lane * 8);
        s = __builtin_amdgcn_mfma_f32_32x32x16_f16(kfa, qf[cs], s, 0, 0, 0);
        half8 kfb = *(const half8*)(Kl + (cs + 1) * 512 + lane * 8);
        s2 = __builtin_amdgcn_mfma_f32_32x32x16_f16(kfb, qf[cs + 1], s2, 0, 0, 0);
      }
    }
    __builtin_amdgcn_s_setprio(0);
#pragma unroll
    for (int i = 0; i < 16; i++) s[i] += s2[i];

    // ---- lazy online softmax (per-lane), tree reductions
    float t0 = fmaxf(s[0], s[1]), t1 = fmaxf(s[2], s[3]);
    float t2 = fmaxf(s[4], s[5]), t3 = fmaxf(s[6], s[7]);
    float t4 = fmaxf(s[8], s[9]), t5 = fmaxf(s[10], s[11]);
    float t6 = fmaxf(s[12], s[13]), t7 = fmaxf(s[14], s[15]);
    t0 = fmaxf(t0, t1); t2 = fmaxf(t2, t3); t4 = fmaxf(t4, t5); t6 = fmaxf(t6, t7);
    float tmax = fmaxf(fmaxf(t0, t2), fmaxf(t4, t6));
    tmax = fmaxf(tmax, __shfl_xor(tmax, 32));
    bool need = tmax > m_run + 8.0f;
    if (__any((int)need)) {
      float mN = need ? tmax : m_run;
      float alpha = __expf(m_run - mN);
      m_run = mN;
      l_run *= alpha;
#pragma unroll
      for (int g = 0; g < 8; g++)
#pragma unroll
        for (int i = 0; i < 16; i++) Oa[g][i] *= alpha;
    }
#pragma unroll
    for (int i = 0; i < 16; i++) s[i] = __expf(s[i] - m_run);
    float u0 = (s[0] + s[1]) + (s[2] + s[3]);
    float u1 = (s[4] + s[5]) + (s[6] + s[7]);
    float u2 = (s[8] + s[9]) + (s[10] + s[11]);
    float u3 = (s[12] + s[13]) + (s[14] + s[15]);
    float ts = (u0 + u1) + (u2 + u3);
    ts += __shfl_xor(ts, 32);
    l_run += ts;

    // ---- P -> registers: pack f16 pairs, swap halves across lane 32 boundary.
    {
      int A01 = packh2(s[0], s[1]), B23 = packh2(s[2], s[3]);
      int C45 = packh2(s[4], s[5]), D67 = packh2(s[6], s[7]);
      int E01 = packh2(s[8], s[9]), F23 = packh2(s[10], s[11]);
      int G45 = packh2(s[12], s[13]), H67 = packh2(s[14], s[15]);
      auto rA = __builtin_amdgcn_permlane32_swap(A01, C45, false, false);
      auto rB = __builtin_amdgcn_permlane32_swap(B23, D67, false, false);
      auto rC = __builtin_amdgcn_permlane32_swap(E01, G45, false, false);
      auto rD = __builtin_amdgcn_permlane32_swap(F23, H67, false, false);
      intx4 w0, w1;
      w0[0] = rA[0]; w0[1] = rB[0]; w0[2] = rA[1]; w0[3] = rB[1];
      w1[0] = rC[0]; w1[1] = rD[0]; w1[2] = rC[1]; w1[3] = rD[1];
      pf0 = __builtin_bit_cast(half8, w0);
      pf1 = __builtin_bit_cast(half8, w1);
    }
  }

  // ---- tail: PV for last tile (ks-outer, same per-chain order)
  asm volatile("s_waitcnt vmcnt(0)" ::: "memory");  // V[KITERS-1] landed
  __builtin_amdgcn_s_barrier();
  {
    const _Float16* Vr = smem + (2 + ((KITERS - 1) & 1)) * 8192;
#pragma unroll
    for (int u = 0; u < 8; u++) {
      half8 vfa = *(const half8*)(Vr + (2 * u) * 512 + lane * 8);
      Oa[u] = __builtin_amdgcn_mfma_f32_32x32x16_f16(vfa, pf0, Oa[u], 0, 0, 0);
    }
#pragma unroll
    for (int u = 0; u < 8; u++) {
      half8 vfb = *(const half8*)(Vr + (2 * u + 1) * 512 + lane * 8);
      Oa[u] = __builtin_amdgcn_mfma_f32_32x32x16_f16(vfb, pf1, Oa[u], 0, 0, 0);
    }
  }

  // ---- epilogue: normalize, per-wave LDS transpose, coalesced store
  float invl = 1.f / l_run;
  __syncthreads();
  float* ot = (float*)smem + wave * (32 * 33);
  _Float16* Opb = Opart + ((size_t)ck * NB + b) * NN * CC;
  const int qr = lane >> 1;
  const int chalf = (lane & 1) * 16;
#pragma unroll
  for (int g = 0; g < 8; g++) {
#pragma unroll
    for (int r = 0; r < 16; r++)
      ot[((r & 3) + 8 * (r >> 2) + 4 * h) * 33 + ql] = Oa[g][r] * invl;
    __builtin_amdgcn_s_waitcnt(WAIT_LGKM0);
    half8 o0, o1;
#pragma unroll
    for (int i = 0; i < 8; i++) o0[i] = (_Float16)ot[(chalf + i) * 33 + qr];
#pragma unroll
    for (int i = 0; i < 8; i++) o1[i] = (_Float16)ot[(chalf + 8 + i) * 33 + qr];
    _Float16* gp = Opb + (size_t)(q0 + qr) * CC + g * 32 + chalf;
    *(half8*)gp = o0;
    *(half8*)(gp + 8) = o1;
    __builtin_amdgcn_s_waitcnt(WAIT_LGKM0);
  }
  if (h == 0) {
    float2 ml; ml.x = m_run; ml.y = l_run;
    Ml[((size_t)ck * NB + b) * NN + q0 + ql] = ml;
  }
}

// ---------------------------------------------------------------------------
// Final conv with fused split-K merge. R6-exact (best measured): K-step 64,
// plain __syncthreads, prefetch after barrier 2. R7/R8 "refinements"
// (K-128, raw barriers, pre-barrier prefetch) both regressed — plateau.
// out[b][d][n] fp32 = Wo . O^T + bo. grid (128, NB), 256 thr, 2 blocks/CU.
// ---------------------------------------------------------------------------
__global__ __launch_bounds__(256, 2) void k_out(const _Float16* __restrict__ Opart,
                                                const float2* __restrict__ Ml,
                                                const float* __restrict__ Wo,
                                                const float* __restrict__ bo,
                                                float* __restrict__ out) {
  __shared__ _Float16 As[64][72];    // 9 KB   (merged O rows, 64-c slice)
  __shared__ _Float16 Bs[128][72];   // 18 KB  (Wo rows, 64-c slice)
  const int bz = blockIdx.y;
  const int mt = blockIdx.x >> 1, nt = blockIdx.x & 1;  // 64 mtiles x 2 ntiles
  const int m0 = mt * 64, n0 = nt * 128;
  const int tid = threadIdx.x;
  const int wave = tid >> 6, lane = tid & 63, quad = lane >> 4, l15 = lane & 15;
  const int wn = wave * 32;

  floatx4 acc[4][2];
#pragma unroll
  for (int i = 0; i < 4; i++)
#pragma unroll
    for (int j = 0; j < 2; j++) acc[i][j] = (floatx4){0.f, 0.f, 0.f, 0.f};

  const int arow = tid >> 2, acol = (tid & 3) * 16;   // A: 64 rows x 64 c
  const int brow = tid >> 1, bcol = (tid & 1) * 32;   // B: 128 rows x 64 c

  // merge weights for this thread's fixed row q = m0 + arow
  const size_t qi = (size_t)bz * NN + m0 + arow;
  float2 a0 = Ml[qi], a1 = Ml[(size_t)NB * NN + qi];
  float2 a2 = Ml[(size_t)2 * NB * NN + qi], a3 = Ml[(size_t)3 * NB * NN + qi];
  float M = fmaxf(fmaxf(a0.x, a1.x), fmaxf(a2.x, a3.x));
  float w0 = __expf(a0.x - M) * a0.y, w1 = __expf(a1.x - M) * a1.y;
  float w2 = __expf(a2.x - M) * a2.y, w3 = __expf(a3.x - M) * a3.y;
  float inv = 1.f / (w0 + w1 + w2 + w3);
  w0 *= inv; w1 *= inv; w2 *= inv; w3 *= inv;
  const size_t ps = (size_t)NB * NN * CC;
  const _Float16* prow = Opart + qi * CC;

  // preload kk=0: 4 planes x 2 half-slices of O, 8 float4 of Wo
  half8 pA[4][2];
  float4 wr[8];
  {
    const _Float16* pr = prow + acol;
#pragma unroll
    for (int pl = 0; pl < 4; pl++) {
      pA[pl][0] = *(const half8*)(pr + (size_t)pl * ps);
      pA[pl][1] = *(const half8*)(pr + (size_t)pl * ps + 8);
    }
    const float4* wp = (const float4*)(Wo + (size_t)(n0 + brow) * 256 + bcol);
#pragma unroll
    for (int i = 0; i < 8; i++) wr[i] = wp[i];
  }

  for (int kk = 0; kk < 256; kk += 64) {
    half8 ma0, ma1;
#pragma unroll
    for (int i = 0; i < 8; i++) {
      ma0[i] = (_Float16)(w0 * (float)pA[0][0][i] + w1 * (float)pA[1][0][i] +
                          w2 * (float)pA[2][0][i] + w3 * (float)pA[3][0][i]);
      ma1[i] = (_Float16)(w0 * (float)pA[0][1][i] + w1 * (float)pA[1][1][i] +
                          w2 * (float)pA[2][1][i] + w3 * (float)pA[3][1][i]);
    }
    half8 bl0, bh0, bl1, bh1;
    cvt16v(wr[0], wr[1], wr[2], wr[3], bl0, bh0);
    cvt16v(wr[4], wr[5], wr[6], wr[7], bl1, bh1);
    __syncthreads();  // prev frag reads done
    *(half8*)&As[arow][acol] = ma0;
    *(half8*)&As[arow][acol + 8] = ma1;
    *(half8*)&Bs[brow][bcol] = bl0;
    *(half8*)&Bs[brow][bcol + 8] = bh0;
    *(half8*)&Bs[brow][bcol + 16] = bl1;
    *(half8*)&Bs[brow][bcol + 24] = bh1;
    __syncthreads();  // tiles visible
    if (kk + 64 < 256) {  // prefetch next slice (in flight across MFMA phase)
      const _Float16* pr = prow + kk + 64 + acol;
#pragma unroll
      for (int pl = 0; pl < 4; pl++) {
        pA[pl][0] = *(const half8*)(pr + (size_t)pl * ps);
        pA[pl][1] = *(const half8*)(pr + (size_t)pl * ps + 8);
      }
      const float4* wp = (const float4*)(Wo + (size_t)(n0 + brow) * 256 + kk + 64 + bcol);
#pragma unroll
      for (int i = 0; i < 8; i++) wr[i] = wp[i];
    }
#pragma unroll
    for (int ks = 0; ks < 2; ks++) {
      half8 af[4], bfr[2];
#pragma unroll
      for (int mb = 0; mb < 4; mb++)
        af[mb] = *(const half8*)&As[mb * 16 + l15][ks * 32 + quad * 8];
#pragma unroll
      for (int nb = 0; nb < 2; nb++)
        bfr[nb] = *(const half8*)&Bs[wn + nb * 16 + l15][ks * 32 + quad * 8];
#pragma unroll
      for (int mb = 0; mb < 4; mb++)
#pragma unroll
        for (int nb = 0; nb < 2; nb++)
          acc[mb][nb] = __builtin_amdgcn_mfma_f32_16x16x32_f16(af[mb], bfr[nb], acc[mb][nb], 0, 0, 0);
    }
  }

  float* op = out + (size_t)bz * NN * CC;
#pragma unroll
  for (int mb = 0; mb < 4; mb++) {
    int nq0 = m0 + mb * 16 + quad * 4;  // spatial
#pragma unroll
    for (int nb = 0; nb < 2; nb++) {
      int d = n0 + wn + nb * 16 + l15;
      float bv = bo[d];
      floatx4 pk;
      pk[0] = acc[mb][nb][0] + bv;
      pk[1] = acc[mb][nb][1] + bv;
      pk[2] = acc[mb][nb][2] + bv;
      pk[3] = acc[mb][nb][3] + bv;
      *(floatx4*)(op + (size_t)d * NN + nq0) = pk;
    }
  }
}

// ---------------------------------------------------------------------------
extern "C" void kernel_launch(void* const* d_in, const int* in_sizes, int n_in,
                              void* d_out, int out_size, void* d_ws, size_t ws_size,
                              hipStream_t stream) {
  const float* Fc = (const float*)d_in[0];
  const float* Fs = (const float*)d_in[1];
  const float* Wf = (const float*)d_in[2];
  const float* bf_ = (const float*)d_in[3];
  const float* Wg = (const float*)d_in[4];
  const float* bg = (const float*)d_in[5];
  const float* Wh = (const float*)d_in[6];
  const float* bh = (const float*)d_in[7];
  const float* Wo = (const float*)d_in[8];
  const float* bo = (const float*)d_in[9];

  char* ws = (char*)d_ws;
  const size_t sz = (size_t)NB * NN * CC * sizeof(_Float16);  // 8 MB per plane
  _Float16* Opart = (_Float16*)(ws + 0 * sz);  // planes 0..3 (split-K partials)
  _Float16* Qs = (_Float16*)(ws + 4 * sz);     // swizzled
  _Float16* Ks = (_Float16*)(ws + 5 * sz);
  _Float16* Vs = (_Float16*)(ws + 6 * sz);
  float2* Ml = (float2*)(ws + 7 * sz);         // 512 KB

  k_qkv<<<dim3(64, NB, 2), 256, 0, stream>>>(Fc, Fs, Wf, Wg, Wh, bf_, bg, bh, Qs, Ks, Vs);
  k_attn<<<dim3(32, 4, NB), 256, 0, stream>>>(Qs, Ks, Vs, Opart, Ml);
  k_out<<<dim3(128, NB), 256, 0, stream>>>(Opart, Ml, Wo, bo, (float*)d_out);
}

// Round 10
// 199.556 us; speedup vs baseline: 1.0168x; 1.0034x over previous
//
#include <hip/hip_runtime.h>
#include <stdint.h>

#define NB 4
#define CC 256
#define NN 4096   // H*W = 64*64
#define KITERS 32 // k-steps per attention chunk (chunk = 1024)
#define WAIT_LGKM0 0xC07F  // s_waitcnt lgkmcnt(0), vmcnt/expcnt untouched

typedef __attribute__((ext_vector_type(8))) _Float16 half8;   // MFMA A/B frag (4 VGPR)
typedef __attribute__((ext_vector_type(4))) _Float16 half4;   // 8B packed store
typedef __attribute__((ext_vector_type(2))) _Float16 half2v;
typedef __attribute__((ext_vector_type(4))) float floatx4;    // 16x16 acc
typedef __attribute__((ext_vector_type(16))) float float16v;  // 32x32 acc
typedef __attribute__((ext_vector_type(4))) int intx4;        // 16B copy

__device__ __forceinline__ void cvt16v(float4 a, float4 b, float4 c, float4 d,
                                       half8& lo, half8& hi) {
  lo[0] = (_Float16)a.x; lo[1] = (_Float16)a.y; lo[2] = (_Float16)a.z; lo[3] = (_Float16)a.w;
  lo[4] = (_Float16)b.x; lo[5] = (_Float16)b.y; lo[6] = (_Float16)b.z; lo[7] = (_Float16)b.w;
  hi[0] = (_Float16)c.x; hi[1] = (_Float16)c.y; hi[2] = (_Float16)c.z; hi[3] = (_Float16)c.w;
  hi[4] = (_Float16)d.x; hi[5] = (_Float16)d.y; hi[6] = (_Float16)d.z; hi[7] = (_Float16)d.w;
}

// pack two f32 -> one u32 of two f16 (RTE, identical to scalar casts)
__device__ __forceinline__ int packh2(float a, float b) {
  half2v p; p[0] = (_Float16)a; p[1] = (_Float16)b;
  return __builtin_bit_cast(int, p);
}

// async global->LDS, 16B per lane; lds dest = wave-uniform base + lane*16.
// PROVEN FORM (R1/R4): global side cast via uintptr, LDS side cast DIRECTLY
// from the generic pointer. PITFALL (R2): LDS side via uintptr_t reinterprets
// the FLAT address as an LDS offset -> garbage.
__device__ __forceinline__ void a16(const _Float16* g, _Float16* l) {
  __builtin_amdgcn_global_load_lds(
      (__attribute__((address_space(1))) void*)(uintptr_t)g,
      (__attribute__((address_space(3))) void*)l, 16, 0, 0);
}

// ---------------------------------------------------------------------------
// Fused transpose + Q/KV projections (R9 body, harness-verified). v18:
// BALANCED lid mapping — grid is a flat 512; lids 0..255 are the 2-unit
// fused-KV blocks, lids 256..511 the 1-unit Q blocks. Under round-robin
// block->CU dispatch each CU gets one KV + one Q = uniform 3 units
// (R9's regression was CUs drawing two 2-unit KV blocks = 4-unit tail).
// z=0: Q = Wf.Fc.  z=1: K = Wg.Fs AND Vt = (Fs^T.Wh^T)^T with the Fs tile
// staged + transposed ONCE for both products.
// 256 threads, 2 blocks/CU (KV 46.9 KB + Q 36.9 KB = 83.8 <= 160).
// ---------------------------------------------------------------------------
__global__ __launch_bounds__(256, 2) void k_qkv(const float* __restrict__ Fc,
                                                const float* __restrict__ Fs,
                                                const float* __restrict__ Wf,
                                                const float* __restrict__ Wg,
                                                const float* __restrict__ Wh,
                                                const float* __restrict__ bf,
                                                const float* __restrict__ bg,
                                                const float* __restrict__ bh,
                                                _Float16* __restrict__ Qs,
                                                _Float16* __restrict__ Ks,
                                                _Float16* __restrict__ Vs) {
  __shared__ float tmp[32][132];     // 16.9 KB fp32 transpose staging
  __shared__ _Float16 Gs[128][40];   // 10 KB: Wf (z=0) or Wg (z=1)
  __shared__ _Float16 Hs[128][40];   // 10 KB: Wh (z=1 only)
  __shared__ _Float16 Xs[128][40];   // 10 KB: F^T slice (n x c)
  const int lid = blockIdx.x;
  const int z = (lid < 256) ? 1 : 0;     // KV blocks first (2-unit), Q second
  const int r = (lid < 256) ? lid : lid - 256;
  const int bz = r >> 6;                  // batch 0..3
  const int t = r & 63;                   // tile 0..63
  const float* F = ((z == 0) ? Fc : Fs) + (size_t)bz * CC * NN;
  const float* W1 = (z == 0) ? Wf : Wg;
  const int wd0 = (t >> 5) * 128;   // W row base (channel side)
  const int xn0 = (t & 31) * 128;   // spatial base of the F tile
  const int tid = threadIdx.x;
  const int wave = tid >> 6, lane = tid & 63, quad = lane >> 4, l15 = lane & 15;
  const int wm = (wave >> 1) * 64, wn = (wave & 1) * 64;

  floatx4 acck[4][4];  // Q (z=0) or K (z=1)
  floatx4 accv[4][4];  // V (z=1 only)
#pragma unroll
  for (int i = 0; i < 4; i++)
#pragma unroll
    for (int j = 0; j < 4; j++) {
      acck[i][j] = (floatx4){0.f, 0.f, 0.f, 0.f};
      accv[i][j] = (floatx4){0.f, 0.f, 0.f, 0.f};
    }

  const int srow = tid >> 1, shalf = (tid & 1) * 16;   // W staging
  const int fc = tid >> 3, fn = (tid & 7) * 16;        // F load (c-row, n-off)
  const int xr = tid >> 1, xh = (tid & 1) * 16;        // transposed read

  float4 wg0, wg1, wg2, wg3, wh0, wh1, wh2, wh3, fr0, fr1, fr2, fr3;
  {
    const float4* wp = (const float4*)(W1 + (size_t)(wd0 + srow) * 256 + 0 + shalf);
    wg0 = wp[0]; wg1 = wp[1]; wg2 = wp[2]; wg3 = wp[3];
    if (z) {
      const float4* hp = (const float4*)(Wh + (size_t)(wd0 + srow) * 256 + 0 + shalf);
      wh0 = hp[0]; wh1 = hp[1]; wh2 = hp[2]; wh3 = hp[3];
    }
    const float4* fp = (const float4*)(F + (size_t)(0 + fc) * NN + xn0 + fn);
    fr0 = fp[0]; fr1 = fp[1]; fr2 = fp[2]; fr3 = fp[3];
  }

  for (int kk = 0; kk < 256; kk += 32) {
    __syncthreads();  // 1: prev frag+tmp reads done
    *(float4*)&tmp[fc][fn + 0] = fr0;
    *(float4*)&tmp[fc][fn + 4] = fr1;
    *(float4*)&tmp[fc][fn + 8] = fr2;
    *(float4*)&tmp[fc][fn + 12] = fr3;
    {
      half8 w_lo, w_hi;
      cvt16v(wg0, wg1, wg2, wg3, w_lo, w_hi);
      *(half8*)&Gs[srow][shalf] = w_lo;
      *(half8*)&Gs[srow][shalf + 8] = w_hi;
      if (z) {
        half8 h_lo, h_hi;
        cvt16v(wh0, wh1, wh2, wh3, h_lo, h_hi);
        *(half8*)&Hs[srow][shalf] = h_lo;
        *(half8*)&Hs[srow][shalf + 8] = h_hi;
      }
    }
    __syncthreads();  // 2: tmp + W-side visible
    if (kk + 32 < 256) {  // prefetch next iter
      const float4* wp = (const float4*)(W1 + (size_t)(wd0 + srow) * 256 + kk + 32 + shalf);
      wg0 = wp[0]; wg1 = wp[1]; wg2 = wp[2]; wg3 = wp[3];
      if (z) {
        const float4* hp = (const float4*)(Wh + (size_t)(wd0 + srow) * 256 + kk + 32 + shalf);
        wh0 = hp[0]; wh1 = hp[1]; wh2 = hp[2]; wh3 = hp[3];
      }
      const float4* fp = (const float4*)(F + (size_t)(kk + 32 + fc) * NN + xn0 + fn);
      fr0 = fp[0]; fr1 = fp[1]; fr2 = fp[2]; fr3 = fp[3];
    }
    half8 xlo, xhi;
#pragma unroll
    for (int i = 0; i < 8; i++) xlo[i] = (_Float16)tmp[xh + i][xr];
#pragma unroll
    for (int i = 0; i < 8; i++) xhi[i] = (_Float16)tmp[xh + 8 + i][xr];
    *(half8*)&Xs[xr][xh] = xlo;
    *(half8*)&Xs[xr][xh + 8] = xhi;
    __syncthreads();  // 3: Gs/Hs/Xs complete
    {
      half8 af[4], bfr[4];
#pragma unroll
      for (int mb = 0; mb < 4; mb++) af[mb] = *(const half8*)&Gs[wm + mb * 16 + l15][quad * 8];
#pragma unroll
      for (int nb = 0; nb < 4; nb++) bfr[nb] = *(const half8*)&Xs[wn + nb * 16 + l15][quad * 8];
#pragma unroll
      for (int mb = 0; mb < 4; mb++)
#pragma unroll
        for (int nb = 0; nb < 4; nb++)
          acck[mb][nb] = __builtin_amdgcn_mfma_f32_16x16x32_f16(af[mb], bfr[nb], acck[mb][nb], 0, 0, 0);
    }
    if (z) {
      half8 av[4], bv[4];
#pragma unroll
      for (int mb = 0; mb < 4; mb++) av[mb] = *(const half8*)&Xs[wm + mb * 16 + l15][quad * 8];
#pragma unroll
      for (int nb = 0; nb < 4; nb++) bv[nb] = *(const half8*)&Hs[wn + nb * 16 + l15][quad * 8];
#pragma unroll
      for (int mb = 0; mb < 4; mb++)
#pragma unroll
        for (int nb = 0; nb < 4; nb++)
          accv[mb][nb] = __builtin_amdgcn_mfma_f32_16x16x32_f16(av[mb], bv[nb], accv[mb][nb], 0, 0, 0);
    }
  }

  {  // Q/K writer (verified geometry: m0:=wd0, n0:=xn0)
    const float* bias = (z == 0) ? bf : bg;
    _Float16* op = (z == 0 ? Qs : Ks) + (size_t)bz * NN * CC;
#pragma unroll
    for (int mb = 0; mb < 4; mb++) {
      int d0 = wd0 + wm + mb * 16 + quad * 4;
      float b0 = bias[d0], b1 = bias[d0 + 1], b2 = bias[d0 + 2], b3 = bias[d0 + 3];
      const int cs = d0 >> 4, hh = (d0 >> 3) & 1, j0 = d0 & 7;
#pragma unroll
      for (int nb = 0; nb < 4; nb++) {
        int n_ = xn0 + wn + nb * 16 + l15;
        int kt = n_ >> 5, ql_ = n_ & 31;
        half4 pk;
        pk[0] = (_Float16)(acck[mb][nb][0] + b0);
        pk[1] = (_Float16)(acck[mb][nb][1] + b1);
        pk[2] = (_Float16)(acck[mb][nb][2] + b2);
        pk[3] = (_Float16)(acck[mb][nb][3] + b3);
        size_t idx = ((size_t)(kt * 16 + cs) * 64 + ql_ + 32 * hh) * 8 + j0;
        *(half4*)(op + idx) = pk;
      }
    }
  }
  if (z) {  // V writer (verified geometry: m:=xn0 spatial, n:=wd0 channel)
    _Float16* op = Vs + (size_t)bz * NN * CC;
#pragma unroll
    for (int mb = 0; mb < 4; mb++) {
      int nq0 = xn0 + wm + mb * 16 + quad * 4;
      const int kt = nq0 >> 5, krel = nq0 & 31;
      const int hk = krel >> 4, hh = (krel >> 3) & 1, j0 = krel & 7;
#pragma unroll
      for (int nb = 0; nb < 4; nb++) {
        int d = wd0 + wn + nb * 16 + l15;
        int ql_ = d & 31, g = (d >> 5) & 7;
        float bv2 = bh[d];
        half4 pk;
        pk[0] = (_Float16)(accv[mb][nb][0] + bv2);
        pk[1] = (_Float16)(accv[mb][nb][1] + bv2);
        pk[2] = (_Float16)(accv[mb][nb][2] + bv2);
        pk[3] = (_Float16)(accv[mb][nb][3] + bv2);
        size_t idx = (((size_t)(kt * 8 + g) * 2 + hk) * 64 + ql_ + 32 * hh) * 8 + j0;
        *(half4*)(op + idx) = pk;
      }
    }
  }
}

// ---------------------------------------------------------------------------
// Flash attention v9 (R1-exact, harness-verified): global_load_lds K/V dbuf,
// 1 barrier/iter, in-register P via cvt_pk+permlane32_swap (DISTINCT operands
// only — R3 pitfall), setprio. grid (32 qtiles, 4 chunks, NB), 256 threads.
// ---------------------------------------------------------------------------
__global__ __launch_bounds__(256, 2) void k_attn(const _Float16* __restrict__ Q,
                                                 const _Float16* __restrict__ K,
                                                 const _Float16* __restrict__ Vt,
                                                 _Float16* __restrict__ Opart,
                                                 float2* __restrict__ Ml) {
  __shared__ _Float16 smem[8192 * 4];  // K dbuf 32KB | V dbuf 32KB
  const int tid = threadIdx.x;
  const int wave = tid >> 6, lane = tid & 63;

  const int qt = blockIdx.x, ck = blockIdx.y, b = blockIdx.z;
  const int ql = lane & 31, h = lane >> 5;
  const int q0 = qt * 128 + wave * 32;
  const _Float16* Qb = Q + (size_t)b * NN * CC;
  const _Float16* Kg = K + (size_t)b * NN * CC;
  const _Float16* Vg = Vt + (size_t)b * NN * CC;
  const int kt_base = ck * KITERS;
  const int so = wave * 512;             // per-wave LDS stage base (halves)
  const int go = wave * 512 + lane * 8;  // per-lane global offset (halves)

  const int ktq = q0 >> 5;
  half8 qf[16];
#pragma unroll
  for (int cs = 0; cs < 16; cs++)
    qf[cs] = *(const half8*)(Qb + ((size_t)(ktq * 16 + cs) * 64 + lane) * 8);

  float16v Oa[8];
#pragma unroll
  for (int g = 0; g < 8; g++)
#pragma unroll
    for (int i = 0; i < 16; i++) Oa[g][i] = 0.f;

  float m_run = -1e30f, l_run = 0.f;
  half8 pf0, pf1;  // previous-iter P fragments, live in registers
#pragma unroll
  for (int i = 0; i < 8; i++) { pf0[i] = (_Float16)0.f; pf1[i] = (_Float16)0.f; }

  // prologue: stage K[0] -> Kbuf0
  {
    const _Float16* Kt = Kg + (size_t)kt_base * 8192;
#pragma unroll
    for (int p = 0; p < 4; p++) a16(Kt + p * 2048 + go, smem + p * 2048 + so);
  }

  for (int t = 0; t < KITERS; t++) {
    asm volatile("s_waitcnt vmcnt(0)" ::: "memory");  // K[t] (+V[t-1]) landed
    __builtin_amdgcn_s_barrier();
    // stage V[t] -> Vbuf[t&1]; K[t+1] -> Kbuf[(t+1)&1]
    {
      const _Float16* Vtile = Vg + (size_t)(kt_base + t) * 8192;
      _Float16* Vw = smem + (2 + (t & 1)) * 8192;
#pragma unroll
      for (int p = 0; p < 4; p++) a16(Vtile + p * 2048 + go, Vw + p * 2048 + so);
      if (t + 1 < KITERS) {
        const _Float16* Kt = Kg + (size_t)(kt_base + t + 1) * 8192;
        _Float16* Kw = smem + ((t + 1) & 1) * 8192;
#pragma unroll
        for (int p = 0; p < 4; p++) a16(Kt + p * 2048 + go, Kw + p * 2048 + so);
      }
    }
    const _Float16* Kl = smem + (t & 1) * 8192;

    // ---- MFMA burst: S_i and PV_i interleaved; PV in ks-outer order:
    //   i<8: Oa[i]   += V[2i]  ·pf0     i>=8: Oa[i-8] += V[2(i-8)+1]·pf1
    float16v s, s2;
#pragma unroll
    for (int i = 0; i < 16; i++) { s[i] = 0.f; s2[i] = 0.f; }
    __builtin_amdgcn_s_setprio(1);
    if (t > 0) {
      const _Float16* Vr = smem + (2 + ((t - 1) & 1)) * 8192;
#pragma unroll
      for (int i = 0; i < 16; i++) {
        half8 kf = *(const half8*)(Kl + i * 512 + lane * 8);
        if (i & 1)
          s2 = __builtin_amdgcn_mfma_f32_32x32x16_f16(kf, qf[i], s2, 0, 0, 0);
        else
          s = __builtin_amdgcn_mfma_f32_32x32x16_f16(kf, qf[i], s, 0, 0, 0);
        const int u = i & 7, ks = i >> 3;
        half8 vf = *(const half8*)(Vr + (2 * u + ks) * 512 + lane * 8);
        Oa[u] = __builtin_amdgcn_mfma_f32_32x32x16_f16(vf, ks ? pf1 : pf0, Oa[u], 0, 0, 0);
      }
    } else {
#pragma unroll
      for (int cs = 0; cs < 16; cs += 2) {
        half8 kfa = *(const half8*)(Kl + cs * 512 + lane * 8);
        s = __builtin_amdgcn_mfma_f32_32x32x16_f16(kfa, qf[cs], s, 0, 0, 0);
        half8 kfb = *(const half8*)(Kl + (cs + 1) * 512 + lane * 8);
        s2 = __builtin_amdgcn_mfma_f32_32x32x16_f16(kfb, qf[cs + 1], s2, 0, 0, 0);
      }
    }
    __builtin_amdgcn_s_setprio(0);
#pragma unroll
    for (int i = 0; i < 16; i++) s[i] += s2[i];

    // ---- lazy online softmax (per-lane), tree reductions
    float t0 = fmaxf(s[0], s[1]), t1 = fmaxf(s[2], s[3]);
    float t2 = fmaxf(s[4], s[5]), t3 = fmaxf(s[6], s[7]);
    float t4 = fmaxf(s[8], s[9]), t5 = fmaxf(s[10], s[11]);
    float t6 = fmaxf(s[12], s[13]), t7 = fmaxf(s[14], s[15]);
    t0 = fmaxf(t0, t1); t2 = fmaxf(t2, t3); t4 = fmaxf(t4, t5); t6 = fmaxf(t6, t7);
    float tmax = fmaxf(fmaxf(t0, t2), fmaxf(t4, t6));
    tmax = fmaxf(tmax, __shfl_xor(tmax, 32));
    bool need = tmax > m_run + 8.0f;
    if (__any((int)need)) {
      float mN = need ? tmax : m_run;
      float alpha = __expf(m_run - mN);
      m_run = mN;
      l_run *= alpha;
#pragma unroll
      for (int g = 0; g < 8; g++)
#pragma unroll
        for (int i = 0; i < 16; i++) Oa[g][i] *= alpha;
    }
#pragma unroll
    for (int i = 0; i < 16; i++) s[i] = __expf(s[i] - m_run);
    float u0 = (s[0] + s[1]) + (s[2] + s[3]);
    float u1 = (s[4] + s[5]) + (s[6] + s[7]);
    float u2 = (s[8] + s[9]) + (s[10] + s[11]);
    float u3 = (s[12] + s[13]) + (s[14] + s[15]);
    float ts = (u0 + u1) + (u2 + u3);
    ts += __shfl_xor(ts, 32);
    l_run += ts;

    // ---- P -> registers: pack f16 pairs, swap halves across lane 32 boundary.
    {
      int A01 = packh2(s[0], s[1]), B23 = packh2(s[2], s[3]);
      int C45 = packh2(s[4], s[5]), D67 = packh2(s[6], s[7]);
      int E01 = packh2(s[8], s[9]), F23 = packh2(s[10], s[11]);
      int G45 = packh2(s[12], s[13]), H67 = packh2(s[14], s[15]);
      auto rA = __builtin_amdgcn_permlane32_swap(A01, C45, false, false);
      auto rB = __builtin_amdgcn_permlane32_swap(B23, D67, false, false);
      auto rC = __builtin_amdgcn_permlane32_swap(E01, G45, false, false);
      auto rD = __builtin_amdgcn_permlane32_swap(F23, H67, false, false);
      intx4 w0, w1;
      w0[0] = rA[0]; w0[1] = rB[0]; w0[2] = rA[1]; w0[3] = rB[1];
      w1[0] = rC[0]; w1[1] = rD[0]; w1[2] = rC[1]; w1[3] = rD[1];
      pf0 = __builtin_bit_cast(half8, w0);
      pf1 = __builtin_bit_cast(half8, w1);
    }
  }

  // ---- tail: PV for last tile (ks-outer, same per-chain order)
  asm volatile("s_waitcnt vmcnt(0)" ::: "memory");  // V[KITERS-1] landed
  __builtin_amdgcn_s_barrier();
  {
    const _Float16* Vr = smem + (2 + ((KITERS - 1) & 1)) * 8192;
#pragma unroll
    for (int u = 0; u < 8; u++) {
      half8 vfa = *(const half8*)(Vr + (2 * u) * 512 + lane * 8);
      Oa[u] = __builtin_amdgcn_mfma_f32_32x32x16_f16(vfa, pf0, Oa[u], 0, 0, 0);
    }
#pragma unroll
    for (int u = 0; u < 8; u++) {
      half8 vfb = *(const half8*)(Vr + (2 * u + 1) * 512 + lane * 8);
      Oa[u] = __builtin_amdgcn_mfma_f32_32x32x16_f16(vfb, pf1, Oa[u], 0, 0, 0);
    }
  }

  // ---- epilogue: normalize, per-wave LDS transpose, coalesced store
  float invl = 1.f / l_run;
  __syncthreads();
  float* ot = (float*)smem + wave * (32 * 33);
  _Float16* Opb = Opart + ((size_t)ck * NB + b) * NN * CC;
  const int qr = lane >> 1;
  const int chalf = (lane & 1) * 16;
#pragma unroll
  for (int g = 0; g < 8; g++) {
#pragma unroll
    for (int r = 0; r < 16; r++)
      ot[((r & 3) + 8 * (r >> 2) + 4 * h) * 33 + ql] = Oa[g][r] * invl;
    __builtin_amdgcn_s_waitcnt(WAIT_LGKM0);
    half8 o0, o1;
#pragma unroll
    for (int i = 0; i < 8; i++) o0[i] = (_Float16)ot[(chalf + i) * 33 + qr];
#pragma unroll
    for (int i = 0; i < 8; i++) o1[i] = (_Float16)ot[(chalf + 8 + i) * 33 + qr];
    _Float16* gp = Opb + (size_t)(q0 + qr) * CC + g * 32 + chalf;
    *(half8*)gp = o0;
    *(half8*)(gp + 8) = o1;
    __builtin_amdgcn_s_waitcnt(WAIT_LGKM0);
  }
  if (h == 0) {
    float2 ml; ml.x = m_run; ml.y = l_run;
    Ml[((size_t)ck * NB + b) * NN + q0 + ql] = ml;
  }
}

// ---------------------------------------------------------------------------
// Final conv with fused split-K merge. R6-exact (best measured): K-step 64,
// plain __syncthreads, prefetch after barrier 2. R7/R8 "refinements"
// (K-128, raw barriers, pre-barrier prefetch) both regressed — plateau.
// out[b][d][n] fp32 = Wo . O^T + bo. grid (128, NB), 256 thr, 2 blocks/CU.
// ---------------------------------------------------------------------------
__global__ __launch_bounds__(256, 2) void k_out(const _Float16* __restrict__ Opart,
                                                const float2* __restrict__ Ml,
                                                const float* __restrict__ Wo,
                                                const float* __restrict__ bo,
                                                float* __restrict__ out) {
  __shared__ _Float16 As[64][72];    // 9 KB   (merged O rows, 64-c slice)
  __shared__ _Float16 Bs[128][72];   // 18 KB  (Wo rows, 64-c slice)
  const int bz = blockIdx.y;
  const int mt = blockIdx.x >> 1, nt = blockIdx.x & 1;  // 64 mtiles x 2 ntiles
  const int m0 = mt * 64, n0 = nt * 128;
  const int tid = threadIdx.x;
  const int wave = tid >> 6, lane = tid & 63, quad = lane >> 4, l15 = lane & 15;
  const int wn = wave * 32;

  floatx4 acc[4][2];
#pragma unroll
  for (int i = 0; i < 4; i++)
#pragma unroll
    for (int j = 0; j < 2; j++) acc[i][j] = (floatx4){0.f, 0.f, 0.f, 0.f};

  const int arow = tid >> 2, acol = (tid & 3) * 16;   // A: 64 rows x 64 c
  const int brow = tid >> 1, bcol = (tid & 1) * 32;   // B: 128 rows x 64 c

  // merge weights for this thread's fixed row q = m0 + arow
  const size_t qi = (size_t)bz * NN + m0 + arow;
  float2 a0 = Ml[qi], a1 = Ml[(size_t)NB * NN + qi];
  float2 a2 = Ml[(size_t)2 * NB * NN + qi], a3 = Ml[(size_t)3 * NB * NN + qi];
  float M = fmaxf(fmaxf(a0.x, a1.x), fmaxf(a2.x, a3.x));
  float w0 = __expf(a0.x - M) * a0.y, w1 = __expf(a1.x - M) * a1.y;
  float w2 = __expf(a2.x - M) * a2.y, w3 = __expf(a3.x - M) * a3.y;
  float inv = 1.f / (w0 + w1 + w2 + w3);
  w0 *= inv; w1 *= inv; w2 *= inv; w3 *= inv;
  const size_t ps = (size_t)NB * NN * CC;
  const _Float16* prow = Opart + qi * CC;

  // preload kk=0: 4 planes x 2 half-slices of O, 8 float4 of Wo
  half8 pA[4][2];
  float4 wr[8];
  {
    const _Float16* pr = prow + acol;
#pragma unroll
    for (int pl = 0; pl < 4; pl++) {
      pA[pl][0] = *(const half8*)(pr + (size_t)pl * ps);
      pA[pl][1] = *(const half8*)(pr + (size_t)pl * ps + 8);
    }
    const float4* wp = (const float4*)(Wo + (size_t)(n0 + brow) * 256 + bcol);
#pragma unroll
    for (int i = 0; i < 8; i++) wr[i] = wp[i];
  }

  for (int kk = 0; kk < 256; kk += 64) {
    half8 ma0, ma1;
#pragma unroll
    for (int i = 0; i < 8; i++) {
      ma0[i] = (_Float16)(w0 * (float)pA[0][0][i] + w1 * (float)pA[1][0][i] +
                          w2 * (float)pA[2][0][i] + w3 * (float)pA[3][0][i]);
      ma1[i] = (_Float16)(w0 * (float)pA[0][1][i] + w1 * (float)pA[1][1][i] +
                          w2 * (float)pA[2][1][i] + w3 * (float)pA[3][1][i]);
    }
    half8 bl0, bh0, bl1, bh1;
    cvt16v(wr[0], wr[1], wr[2], wr[3], bl0, bh0);
    cvt16v(wr[4], wr[5], wr[6], wr[7], bl1, bh1);
    __syncthreads();  // prev frag reads done
    *(half8*)&As[arow][acol] = ma0;
    *(half8*)&As[arow][acol + 8] = ma1;
    *(half8*)&Bs[brow][bcol] = bl0;
    *(half8*)&Bs[brow][bcol + 8] = bh0;
    *(half8*)&Bs[brow][bcol + 16] = bl1;
    *(half8*)&Bs[brow][bcol + 24] = bh1;
    __syncthreads();  // tiles visible
    if (kk + 64 < 256) {  // prefetch next slice (in flight across MFMA phase)
      const _Float16* pr = prow + kk + 64 + acol;
#pragma unroll
      for (int pl = 0; pl < 4; pl++) {
        pA[pl][0] = *(const half8*)(pr + (size_t)pl * ps);
        pA[pl][1] = *(const half8*)(pr + (size_t)pl * ps + 8);
      }
      const float4* wp = (const float4*)(Wo + (size_t)(n0 + brow) * 256 + kk + 64 + bcol);
#pragma unroll
      for (int i = 0; i < 8; i++) wr[i] = wp[i];
    }
#pragma unroll
    for (int ks = 0; ks < 2; ks++) {
      half8 af[4], bfr[2];
#pragma unroll
      for (int mb = 0; mb < 4; mb++)
        af[mb] = *(const half8*)&As[mb * 16 + l15][ks * 32 + quad * 8];
#pragma unroll
      for (int nb = 0; nb < 2; nb++)
        bfr[nb] = *(const half8*)&Bs[wn + nb * 16 + l15][ks * 32 + quad * 8];
#pragma unroll
      for (int mb = 0; mb < 4; mb++)
#pragma unroll
        for (int nb = 0; nb < 2; nb++)
          acc[mb][nb] = __builtin_amdgcn_mfma_f32_16x16x32_f16(af[mb], bfr[nb], acc[mb][nb], 0, 0, 0);
    }
  }

  float* op = out + (size_t)bz * NN * CC;
#pragma unroll
  for (int mb = 0; mb < 4; mb++) {
    int nq0 = m0 + mb * 16 + quad * 4;  // spatial
#pragma unroll
    for (int nb = 0; nb < 2; nb++) {
      int d = n0 + wn + nb * 16 + l15;
      float bv = bo[d];
      floatx4 pk;
      pk[0] = acc[mb][nb][0] + bv;
      pk[1] = acc[mb][nb][1] + bv;
      pk[2] = acc[mb][nb][2] + bv;
      pk[3] = acc[mb][nb][3] + bv;
      *(floatx4*)(op + (size_t)d * NN + nq0) = pk;
    }
  }
}

// ---------------------------------------------------------------------------
extern "C" void kernel_launch(void* const* d_in, const int* in_sizes, int n_in,
                              void* d_out, int out_size, void* d_ws, size_t ws_size,
                              hipStream_t stream) {
  const float* Fc = (const float*)d_in[0];
  const float* Fs = (const float*)d_in[1];
  const float* Wf = (const float*)d_in[2];
  const float* bf_ = (const float*)d_in[3];
  const float* Wg = (const float*)d_in[4];
  const float* bg = (const float*)d_in[5];
  const float* Wh = (const float*)d_in[6];
  const float* bh = (const float*)d_in[7];
  const float* Wo = (const float*)d_in[8];
  const float* bo = (const float*)d_in[9];

  char* ws = (char*)d_ws;
  const size_t sz = (size_t)NB * NN * CC * sizeof(_Float16);  // 8 MB per plane
  _Float16* Opart = (_Float16*)(ws + 0 * sz);  // planes 0..3 (split-K partials)
  _Float16* Qs = (_Float16*)(ws + 4 * sz);     // swizzled
  _Float16* Ks = (_Float16*)(ws + 5 * sz);
  _Float16* Vs = (_Float16*)(ws + 6 * sz);
  float2* Ml = (float2*)(ws + 7 * sz);         // 512 KB

  k_qkv<<<dim3(512, 1, 1), 256, 0, stream>>>(Fc, Fs, Wf, Wg, Wh, bf_, bg, bh, Qs, Ks, Vs);
  k_attn<<<dim3(32, 4, NB), 256, 0, stream>>>(Qs, Ks, Vs, Opart, Ml);
  k_out<<<dim3(128, NB), 256, 0, stream>>>(Opart, Ml, Wo, bo, (float*)d_out);
}